// Round 9
// baseline (244.850 us; speedup 1.0000x reference)
//
#include <hip/hip_runtime.h>

#define C_DIM 512
#define N_PIX 1024
#define B_DIM 8
#define NHEAD 8
#define HDIM 64
#define NGRP 8
#define CG 64
#define EPSF 1e-5f

typedef __bf16 bf16x8_t __attribute__((ext_vector_type(8)));
typedef __bf16 bf16x4_t __attribute__((ext_vector_type(4)));
typedef float  f32x4_t  __attribute__((ext_vector_type(4)));
typedef unsigned int u32x4_t __attribute__((ext_vector_type(4)));

__device__ __forceinline__ __bf16 f2b(float f) {
  unsigned int u = __builtin_bit_cast(unsigned int, f);
  u += 0x7fffu + ((u >> 16) & 1u);
  unsigned short s = (unsigned short)(u >> 16);
  return __builtin_bit_cast(__bf16, s);
}

// truncating pack: two fp32 -> packed bf16 pair (low=a, high=b); P>=0 so safe
__device__ __forceinline__ unsigned int pack_trunc(float a, float b) {
  return (__builtin_bit_cast(unsigned int, a) >> 16) |
         (__builtin_bit_cast(unsigned int, b) & 0xffff0000u);
}

__device__ __forceinline__ void async16(const void* g, void* l) {
  __builtin_amdgcn_global_load_lds((const __attribute__((address_space(1))) void*)g,
                                   (__attribute__((address_space(3))) void*)l, 16, 0, 0);
}

// ---------------- prep: weight fp32->bf16 (blocks 0..1023) + GN stats (1024..1535) ----------------
__global__ __launch_bounds__(256) void prep_kernel(
    const float* __restrict__ qw, const float* __restrict__ kw,
    const float* __restrict__ vw, const float* __restrict__ pw,
    __bf16* __restrict__ wb,
    const float* __restrict__ x, float2* __restrict__ psum)
{
  if (blockIdx.x < 1024) {
    int idx = blockIdx.x * 256 + threadIdx.x;
    int mat = idx >> 16;
    int off = (idx & 65535) * 4;
    const float* src = (mat == 0) ? qw : (mat == 1) ? kw : (mat == 2) ? vw : pw;
    float4 v = *(const float4*)(src + off);
    bf16x4_t pk;
    pk[0] = f2b(v.x); pk[1] = f2b(v.y); pk[2] = f2b(v.z); pk[3] = f2b(v.w);
    *(bf16x4_t*)(wb + mat * (512 * 512) + off) = pk;
  } else {
    const int t = blockIdx.x - 1024;
    const int s = t & 7, bg = t >> 3;
    const float* xp = x + ((size_t)bg * CG + s * 8) * N_PIX;
    float sum = 0.f, sum2 = 0.f;
#pragma unroll
    for (int it = 0; it < 8; it++) {
      float4 v = ((const float4*)xp)[it * 256 + threadIdx.x];
      sum  += v.x + v.y + v.z + v.w;
      sum2 += v.x * v.x + v.y * v.y + v.z * v.z + v.w * v.w;
    }
#pragma unroll
    for (int off = 32; off; off >>= 1) {
      sum  += __shfl_xor(sum, off, 64);
      sum2 += __shfl_xor(sum2, off, 64);
    }
    __shared__ float red[8];
    const int lane = threadIdx.x & 63, wv = threadIdx.x >> 6;
    if (lane == 0) { red[wv] = sum; red[4 + wv] = sum2; }
    __syncthreads();
    if (threadIdx.x == 0) {
      float s1 = red[0] + red[1] + red[2] + red[3];
      float s2 = red[4] + red[5] + red[6] + red[7];
      psum[bg * 8 + s] = make_float2(s1, s2);
    }
  }
}

// ---------------- GroupNorm apply + transpose -> xnT bf16 [B][N][C] ----------------
__global__ __launch_bounds__(256) void gn_apply_kernel(
    const float* __restrict__ x, const float2* __restrict__ psum,
    const float* __restrict__ gw, const float* __restrict__ gb,
    __bf16* __restrict__ xnT)
{
  const int n0 = blockIdx.x * 32, b = blockIdx.y;
  const int tid = threadIdx.x;
  __shared__ float mu_s[8], rs_s[8];
  __shared__ __align__(16) __bf16 tile[32 * 520];

  if (tid < 8) {
    float s1 = 0.f, s2 = 0.f;
#pragma unroll
    for (int i = 0; i < 8; i++) {
      float2 p = psum[(b * 8 + tid) * 8 + i];
      s1 += p.x; s2 += p.y;
    }
    const float inv = 1.f / (float)(CG * N_PIX);
    float mu = s1 * inv;
    float var = s2 * inv - mu * mu;
    mu_s[tid] = mu;
    rs_s[tid] = rsqrtf(var + EPSF);
  }
  __syncthreads();

  const float* xb = x + (size_t)b * C_DIM * N_PIX + n0;
  const int cl = tid >> 3;
  const int nq = (tid & 7) * 4;
#pragma unroll
  for (int co = 0; co < 16; co++) {
    const int c = co * 32 + cl;
    float4 v = *(const float4*)(xb + (size_t)c * N_PIX + nq);
    const int g = c >> 6;
    const float rs = rs_s[g];
    const float a = rs * gw[c];
    const float bb = gb[c] - mu_s[g] * a;
    tile[(nq + 0) * 520 + c] = f2b(v.x * a + bb);
    tile[(nq + 1) * 520 + c] = f2b(v.y * a + bb);
    tile[(nq + 2) * 520 + c] = f2b(v.z * a + bb);
    tile[(nq + 3) * 520 + c] = f2b(v.w * a + bb);
  }
  __syncthreads();

  __bf16* dst = xnT + ((size_t)b * N_PIX + n0) * C_DIM;
  const int l32 = tid & 31, nr = tid >> 5;
#pragma unroll
  for (int no = 0; no < 4; no++) {
    const int n = no * 8 + nr;
#pragma unroll
    for (int co = 0; co < 2; co++) {
      const int c = co * 256 + l32 * 8;
      *(bf16x8_t*)(dst + (size_t)n * C_DIM + c) =
          *(const bf16x8_t*)(tile + n * 520 + c);
    }
  }
}

// ---------------- 128x128 gemm_bt core, BK=64 as two 32-col panels (K=512) ----------------
__device__ __forceinline__ void gemm_core_128(
    const __bf16* __restrict__ A, const __bf16* __restrict__ B,
    __bf16* As, __bf16* Bs, f32x4_t acc[4][4])
{
  const int tid  = threadIdx.x;
  const int lane = tid & 63;
  const int wv   = tid >> 6;
  const int quad = lane >> 4;
  const int l16  = lane & 15;
  const int wm = (wv >> 1) * 64;
  const int wn = (wv & 1) * 64;

  f32x4_t zero = {0.f, 0.f, 0.f, 0.f};
#pragma unroll
  for (int i = 0; i < 4; i++)
#pragma unroll
    for (int j = 0; j < 4; j++) acc[i][j] = zero;

  const int chb0 = wv * 128;
  const int chb1 = wv * 128 + 64;
  const int ch0 = chb0 + lane, ch1 = chb1 + lane;
  const int r0 = ch0 >> 2, k0 = (ch0 & 3) * 8;
  const int r1 = ch1 >> 2, k1 = (ch1 & 3) * 8;

  for (int kt = 0; kt < 512; kt += 64) {
#pragma unroll
    for (int p = 0; p < 2; p++) {
      async16(A + (size_t)r0 * 512 + kt + p * 32 + k0, As + p * 4096 + chb0 * 8);
      async16(A + (size_t)r1 * 512 + kt + p * 32 + k1, As + p * 4096 + chb1 * 8);
      async16(B + (size_t)r0 * 512 + kt + p * 32 + k0, Bs + p * 4096 + chb0 * 8);
      async16(B + (size_t)r1 * 512 + kt + p * 32 + k1, Bs + p * 4096 + chb1 * 8);
    }
    __builtin_amdgcn_s_waitcnt(0);
    __syncthreads();
#pragma unroll
    for (int p = 0; p < 2; p++) {
      bf16x8_t af[4], bfr[4];
#pragma unroll
      for (int i = 0; i < 4; i++)
        af[i] = *(const bf16x8_t*)(As + p * 4096 + (wm + i * 16 + l16) * 32 + quad * 8);
#pragma unroll
      for (int j = 0; j < 4; j++)
        bfr[j] = *(const bf16x8_t*)(Bs + p * 4096 + (wn + j * 16 + l16) * 32 + quad * 8);
#pragma unroll
      for (int i = 0; i < 4; i++)
#pragma unroll
        for (int j = 0; j < 4; j++)
          acc[i][j] = __builtin_amdgcn_mfma_f32_16x16x32_bf16(af[i], bfr[j], acc[i][j], 0, 0, 0);
    }
    __syncthreads();
  }
}

// ---------------- QKV gemm: grid (8=b, 8=n, 12=mat*4+m) ----------------
__global__ __launch_bounds__(256) void gemm_qkv_kernel(
    const __bf16* __restrict__ wqkv, const float* __restrict__ qb,
    const float* __restrict__ kb, const float* __restrict__ vb,
    const __bf16* __restrict__ xnT,
    __bf16* __restrict__ qT, __bf16* __restrict__ kT, __bf16* __restrict__ vbuf)
{
  __shared__ __align__(16) __bf16 smem[16384];   // 32 KB: As|Bs, re-used as V-transpose tile
  __bf16* As = smem;
  __bf16* Bs = smem + 8192;
  const int b = blockIdx.x;
  const int n0 = blockIdx.y * 128;
  const int mat = blockIdx.z >> 2;
  const int m0 = (blockIdx.z & 3) * 128;
  const __bf16* A = wqkv + (size_t)mat * (512 * 512) + (size_t)m0 * 512;
  const __bf16* B = xnT + ((size_t)b * N_PIX + n0) * 512;
  f32x4_t acc[4][4];
  gemm_core_128(A, B, As, Bs, acc);

  const int tid = threadIdx.x, lane = tid & 63, wv = tid >> 6;
  const int quad = lane >> 4, l16 = lane & 15;
  const int wm = (wv >> 1) * 64, wn = (wv & 1) * 64;
  const float* bias = (mat == 0) ? qb : (mat == 1) ? kb : vb;
  const float qscale = (mat == 0) ? 0.125f * 1.44269504f : 1.0f;  // HD^-0.5 * log2(e)

  if (mat < 2) {
    __bf16* dst = (mat == 0) ? qT : kT;
#pragma unroll
    for (int i = 0; i < 4; i++) {
      const int o = m0 + wm + i * 16 + quad * 4;
      float b0 = bias[o], b1 = bias[o + 1], b2 = bias[o + 2], b3 = bias[o + 3];
#pragma unroll
      for (int j = 0; j < 4; j++) {
        const int n = n0 + wn + j * 16 + l16;
        bf16x4_t pk;
        pk[0] = f2b((acc[i][j][0] + b0) * qscale);
        pk[1] = f2b((acc[i][j][1] + b1) * qscale);
        pk[2] = f2b((acc[i][j][2] + b2) * qscale);
        pk[3] = f2b((acc[i][j][3] + b3) * qscale);
        *(bf16x4_t*)(dst + ((size_t)b * N_PIX + n) * 512 + o) = pk;
      }
    }
  } else {
    // two half-tile passes through LDS (stride 132 breaks bank conflicts)
#pragma unroll
    for (int p = 0; p < 2; p++) {
      __syncthreads();
      if ((wv >> 1) == p) {
#pragma unroll
        for (int i = 0; i < 4; i++) {
          const int crow = i * 16 + quad * 4;           // 0..63 within half
          const int o = m0 + p * 64 + crow;
          float b0 = bias[o], b1 = bias[o + 1], b2 = bias[o + 2], b3 = bias[o + 3];
#pragma unroll
          for (int j = 0; j < 4; j++) {
            const int nl = wn + j * 16 + l16;
            smem[(crow + 0) * 132 + nl] = f2b(acc[i][j][0] + b0);
            smem[(crow + 1) * 132 + nl] = f2b(acc[i][j][1] + b1);
            smem[(crow + 2) * 132 + nl] = f2b(acc[i][j][2] + b2);
            smem[(crow + 3) * 132 + nl] = f2b(acc[i][j][3] + b3);
          }
        }
      }
      __syncthreads();
      const int c = tid >> 2;                 // 0..63
      const int cg = m0 + p * 64 + c;
      const int nch = (tid & 3) * 32;
      __bf16* vd = vbuf + ((size_t)b * 512 + cg) * N_PIX + n0 + nch;
#pragma unroll
      for (int k = 0; k < 4; k++)
        *(bf16x8_t*)(vd + k * 8) = *(const bf16x8_t*)(smem + c * 132 + nch + k * 8);
    }
  }
}

// ---------------- attention: 32 q/wave, permuted V, double-buffered (1 barrier/iter) ----------------
__global__ __launch_bounds__(256, 2) void attn_kernel(
    const __bf16* __restrict__ qT, const __bf16* __restrict__ kT,
    const __bf16* __restrict__ vbuf, __bf16* __restrict__ aT)
{
  __shared__ __align__(16) __bf16 Ks[2][64 * 72];
  __shared__ __align__(16) __bf16 Vp[2][64 * 72];
  const int bh = blockIdx.x;
  const int b = bh >> 3, head = bh & 7;
  const int n0 = blockIdx.y * 128;
  const int tid = threadIdx.x, lane = tid & 63, wv = tid >> 6;
  const int quad = lane >> 4, l16 = lane & 15;

  bf16x8_t qf[2][2];
#pragma unroll
  for (int qt = 0; qt < 2; qt++) {
    const __bf16* qp = qT + ((size_t)b * N_PIX + n0 + wv * 32 + qt * 16 + l16) * 512 + head * 64;
    qf[qt][0] = *(const bf16x8_t*)(qp + quad * 8);
    qf[qt][1] = *(const bf16x8_t*)(qp + 32 + quad * 8);
  }

  const __bf16* kp = kT + ((size_t)b * N_PIX) * 512 + head * 64;
  const __bf16* vp = vbuf + ((size_t)b * 512 + head * 64) * N_PIX;

  const int srow = tid >> 2, scol = (tid & 3) * 16;
  const int pr0 = scol >> 5, hh0 = (scol >> 4) & 1;
  const int pos0 = pr0 * 32 + ((scol >> 2) & 3) * 8 + hh0 * 4;
  const int mc1 = scol + 8;
  const int pr1 = mc1 >> 5, hh1 = (mc1 >> 4) & 1;
  const int pos1 = pr1 * 32 + ((mc1 >> 2) & 3) * 8 + hh1 * 4;

  bf16x8_t kreg0 = *(const bf16x8_t*)(kp + (size_t)srow * 512 + scol);
  bf16x8_t kreg1 = *(const bf16x8_t*)(kp + (size_t)srow * 512 + scol + 8);
  bf16x8_t vreg0 = *(const bf16x8_t*)(vp + (size_t)srow * N_PIX + scol);
  bf16x8_t vreg1 = *(const bf16x8_t*)(vp + (size_t)srow * N_PIX + scol + 8);
  {
    *(bf16x8_t*)(Ks[0] + srow * 72 + scol)     = kreg0;
    *(bf16x8_t*)(Ks[0] + srow * 72 + scol + 8) = kreg1;
    bf16x4_t lo, hi;
#pragma unroll
    for (int r = 0; r < 4; r++) { lo[r] = vreg0[r]; hi[r] = vreg0[4 + r]; }
    *(bf16x4_t*)(Vp[0] + srow * 72 + pos0)     = lo;
    *(bf16x4_t*)(Vp[0] + srow * 72 + pos0 + 8) = hi;
#pragma unroll
    for (int r = 0; r < 4; r++) { lo[r] = vreg1[r]; hi[r] = vreg1[4 + r]; }
    *(bf16x4_t*)(Vp[0] + srow * 72 + pos1)     = lo;
    *(bf16x4_t*)(Vp[0] + srow * 72 + pos1 + 8) = hi;
  }
  kreg0 = *(const bf16x8_t*)(kp + (size_t)(64 + srow) * 512 + scol);
  kreg1 = *(const bf16x8_t*)(kp + (size_t)(64 + srow) * 512 + scol + 8);
  vreg0 = *(const bf16x8_t*)(vp + (size_t)srow * N_PIX + 64 + scol);
  vreg1 = *(const bf16x8_t*)(vp + (size_t)srow * N_PIX + 64 + scol + 8);
  __syncthreads();

  const f32x4_t zero = {0.f, 0.f, 0.f, 0.f};
  f32x4_t oacc[2][4];
#pragma unroll
  for (int qt = 0; qt < 2; qt++)
#pragma unroll
    for (int jc = 0; jc < 4; jc++) oacc[qt][jc] = zero;
  f32x4_t lsum4[2] = {zero, zero};

  for (int mt = 0; mt < 16; mt++) {
    const int cur = mt & 1, nxt = cur ^ 1;
    const __bf16* Kc = Ks[cur];
    const __bf16* Vc = Vp[cur];

    f32x4_t sacc[2][4];
#pragma unroll
    for (int mb = 0; mb < 4; mb++) {
      bf16x8_t kf0 = *(const bf16x8_t*)(Kc + (mb * 16 + l16) * 72 + quad * 8);
      bf16x8_t kf1 = *(const bf16x8_t*)(Kc + (mb * 16 + l16) * 72 + 32 + quad * 8);
#pragma unroll
      for (int qt = 0; qt < 2; qt++) {
        f32x4_t s = zero;
        s = __builtin_amdgcn_mfma_f32_16x16x32_bf16(kf0, qf[qt][0], s, 0, 0, 0);
        s = __builtin_amdgcn_mfma_f32_16x16x32_bf16(kf1, qf[qt][1], s, 0, 0, 0);
        sacc[qt][mb] = s;
      }
    }

    bf16x8_t pf[2][2];
#pragma unroll
    for (int qt = 0; qt < 2; qt++) {
      float p[4][4];
#pragma unroll
      for (int mb = 0; mb < 4; mb++)
#pragma unroll
        for (int r = 0; r < 4; r++) {
          p[mb][r] = __builtin_amdgcn_exp2f(sacc[qt][mb][r]);
          lsum4[qt][r] += p[mb][r];
        }
#pragma unroll
      for (int pr = 0; pr < 2; pr++) {
        u32x4_t u;
        u[0] = pack_trunc(p[2 * pr][0],     p[2 * pr][1]);
        u[1] = pack_trunc(p[2 * pr][2],     p[2 * pr][3]);
        u[2] = pack_trunc(p[2 * pr + 1][0], p[2 * pr + 1][1]);
        u[3] = pack_trunc(p[2 * pr + 1][2], p[2 * pr + 1][3]);
        pf[qt][pr] = __builtin_bit_cast(bf16x8_t, u);
      }
    }

#pragma unroll
    for (int jc = 0; jc < 4; jc++) {
      const int vrow = (jc * 16 + l16) * 72;
#pragma unroll
      for (int pr = 0; pr < 2; pr++) {
        bf16x8_t vf = *(const bf16x8_t*)(Vc + vrow + pr * 32 + quad * 8);
#pragma unroll
        for (int qt = 0; qt < 2; qt++)
          oacc[qt][jc] = __builtin_amdgcn_mfma_f32_16x16x32_bf16(vf, pf[qt][pr], oacc[qt][jc], 0, 0, 0);
      }
    }

    if (mt < 15) {
      *(bf16x8_t*)(Ks[nxt] + srow * 72 + scol)     = kreg0;
      *(bf16x8_t*)(Ks[nxt] + srow * 72 + scol + 8) = kreg1;
      bf16x4_t lo, hi;
#pragma unroll
      for (int r = 0; r < 4; r++) { lo[r] = vreg0[r]; hi[r] = vreg0[4 + r]; }
      *(bf16x4_t*)(Vp[nxt] + srow * 72 + pos0)     = lo;
      *(bf16x4_t*)(Vp[nxt] + srow * 72 + pos0 + 8) = hi;
#pragma unroll
      for (int r = 0; r < 4; r++) { lo[r] = vreg1[r]; hi[r] = vreg1[4 + r]; }
      *(bf16x4_t*)(Vp[nxt] + srow * 72 + pos1)     = lo;
      *(bf16x4_t*)(Vp[nxt] + srow * 72 + pos1 + 8) = hi;
      if (mt < 14) {
        kreg0 = *(const bf16x8_t*)(kp + (size_t)((mt + 2) * 64 + srow) * 512 + scol);
        kreg1 = *(const bf16x8_t*)(kp + (size_t)((mt + 2) * 64 + srow) * 512 + scol + 8);
        vreg0 = *(const bf16x8_t*)(vp + (size_t)srow * N_PIX + (mt + 2) * 64 + scol);
        vreg1 = *(const bf16x8_t*)(vp + (size_t)srow * N_PIX + (mt + 2) * 64 + scol + 8);
      }
      __syncthreads();
    }
  }

#pragma unroll
  for (int qt = 0; qt < 2; qt++) {
    float lsum = lsum4[qt][0] + lsum4[qt][1] + lsum4[qt][2] + lsum4[qt][3];
    lsum += __shfl_xor(lsum, 16, 64);
    lsum += __shfl_xor(lsum, 32, 64);
    const float inv = 1.f / lsum;
    __bf16* op = aT + ((size_t)b * N_PIX + n0 + wv * 32 + qt * 16 + l16) * 512 + head * 64;
#pragma unroll
    for (int jc = 0; jc < 4; jc++) {
      bf16x4_t o4;
#pragma unroll
      for (int r = 0; r < 4; r++) o4[r] = f2b(oacc[qt][jc][r] * inv);
      *(bf16x4_t*)(op + jc * 16 + quad * 4) = o4;
    }
  }
}

// ---------------- proj gemm + bias + residual: grid (8=b, 8=n, 4=m) ----------------
__global__ __launch_bounds__(256) void gemm_proj_kernel(
    const __bf16* __restrict__ wp, const float* __restrict__ pb,
    const __bf16* __restrict__ aT, const float* __restrict__ x,
    float* __restrict__ out)
{
  __shared__ __align__(16) __bf16 As[8192];
  __shared__ __align__(16) __bf16 Bs[8192];
  const int b = blockIdx.x;
  const int n0 = blockIdx.y * 128;
  const int m0 = blockIdx.z * 128;
  const __bf16* A = wp + (size_t)m0 * 512;
  const __bf16* B = aT + ((size_t)b * N_PIX + n0) * 512;
  f32x4_t acc[4][4];
  gemm_core_128(A, B, As, Bs, acc);
  const int tid = threadIdx.x, lane = tid & 63, wv = tid >> 6;
  const int quad = lane >> 4, l16 = lane & 15;
  const int wm = (wv >> 1) * 64, wn = (wv & 1) * 64;
#pragma unroll
  for (int i = 0; i < 4; i++) {
    const int o = m0 + wm + i * 16 + quad * 4;
#pragma unroll
    for (int j = 0; j < 4; j++) {
      const int n = n0 + wn + j * 16 + l16;
#pragma unroll
      for (int r = 0; r < 4; r++) {
        size_t idx = ((size_t)b * 512 + o + r) * N_PIX + n;
        out[idx] = acc[i][j][r] + pb[o + r] + x[idx];
      }
    }
  }
}

extern "C" void kernel_launch(void* const* d_in, const int* in_sizes, int n_in,
                              void* d_out, int out_size, void* d_ws, size_t ws_size,
                              hipStream_t stream)
{
  (void)in_sizes; (void)n_in; (void)out_size; (void)ws_size;
  const float* x   = (const float*)d_in[0];
  const float* gnw = (const float*)d_in[1];
  const float* gnb = (const float*)d_in[2];
  const float* qw  = (const float*)d_in[3];
  const float* qb  = (const float*)d_in[4];
  const float* kw  = (const float*)d_in[5];
  const float* kb  = (const float*)d_in[6];
  const float* vw  = (const float*)d_in[7];
  const float* vb  = (const float*)d_in[8];
  const float* pw  = (const float*)d_in[9];
  const float* pb  = (const float*)d_in[10];
  float* out = (float*)d_out;

  char* ws = (char*)d_ws;
  __bf16* wb   = (__bf16*)(ws);                         // 2 MB
  __bf16* xnT  = (__bf16*)(ws + (size_t)(2  << 20));    // 8 MB
  __bf16* qTb  = (__bf16*)(ws + (size_t)(10 << 20));    // 8 MB
  __bf16* kTb  = (__bf16*)(ws + (size_t)(18 << 20));    // 8 MB
  __bf16* vbf  = (__bf16*)(ws + (size_t)(26 << 20));    // 8 MB
  __bf16* aT   = (__bf16*)(ws + (size_t)(34 << 20));    // 8 MB
  float2* psum = (float2*)(ws + (size_t)(42 << 20));    // 4 KB

  // MEASUREMENT ROUND: every kernel launched TWICE (idempotent — same inputs
  // produce same outputs, so final state and absmax are bit-identical).
  //   sum_of_our_kernels = dur(R9) - dur(R8)
  //   fixed_overhead     = 2*dur(R8) - dur(R9)
  hipLaunchKernelGGL(prep_kernel, dim3(1536), dim3(256), 0, stream,
                     qw, kw, vw, pw, wb, x, psum);
  hipLaunchKernelGGL(prep_kernel, dim3(1536), dim3(256), 0, stream,
                     qw, kw, vw, pw, wb, x, psum);
  hipLaunchKernelGGL(gn_apply_kernel, dim3(32, 8), dim3(256), 0, stream, x, psum, gnw, gnb, xnT);
  hipLaunchKernelGGL(gn_apply_kernel, dim3(32, 8), dim3(256), 0, stream, x, psum, gnw, gnb, xnT);
  hipLaunchKernelGGL(gemm_qkv_kernel, dim3(8, 8, 12), dim3(256), 0, stream,
                     wb, qb, kb, vb, xnT, qTb, kTb, vbf);
  hipLaunchKernelGGL(gemm_qkv_kernel, dim3(8, 8, 12), dim3(256), 0, stream,
                     wb, qb, kb, vb, xnT, qTb, kTb, vbf);
  hipLaunchKernelGGL(attn_kernel, dim3(64, 8), dim3(256), 0, stream, qTb, kTb, vbf, aT);
  hipLaunchKernelGGL(attn_kernel, dim3(64, 8), dim3(256), 0, stream, qTb, kTb, vbf, aT);
  hipLaunchKernelGGL(gemm_proj_kernel, dim3(8, 8, 4), dim3(256), 0, stream,
                     wb + (size_t)3 * 512 * 512, pb, aT, x, out);
  hipLaunchKernelGGL(gemm_proj_kernel, dim3(8, 8, 4), dim3(256), 0, stream,
                     wb + (size_t)3 * 512 * 512, pb, aT, x, out);
}

// Round 10
// 153.726 us; speedup vs baseline: 1.5928x; 1.5928x over previous
//
#include <hip/hip_runtime.h>

#define C_DIM 512
#define N_PIX 1024
#define B_DIM 8
#define NHEAD 8
#define HDIM 64
#define NGRP 8
#define CG 64
#define EPSF 1e-5f

typedef __bf16 bf16x8_t __attribute__((ext_vector_type(8)));
typedef __bf16 bf16x4_t __attribute__((ext_vector_type(4)));
typedef float  f32x4_t  __attribute__((ext_vector_type(4)));
typedef unsigned int u32x4_t __attribute__((ext_vector_type(4)));

__device__ __forceinline__ __bf16 f2b(float f) {
  unsigned int u = __builtin_bit_cast(unsigned int, f);
  u += 0x7fffu + ((u >> 16) & 1u);
  unsigned short s = (unsigned short)(u >> 16);
  return __builtin_bit_cast(__bf16, s);
}

// truncating pack: two fp32 -> packed bf16 pair (low=a, high=b); P>=0 so safe
__device__ __forceinline__ unsigned int pack_trunc(float a, float b) {
  return (__builtin_bit_cast(unsigned int, a) >> 16) |
         (__builtin_bit_cast(unsigned int, b) & 0xffff0000u);
}

__device__ __forceinline__ void async16(const void* g, void* l) {
  __builtin_amdgcn_global_load_lds((const __attribute__((address_space(1))) void*)g,
                                   (__attribute__((address_space(3))) void*)l, 16, 0, 0);
}

// ---------------- prep: weight fp32->bf16 (blocks 0..1023) + GN stats (1024..1535) ----------------
__global__ __launch_bounds__(256) void prep_kernel(
    const float* __restrict__ qw, const float* __restrict__ kw,
    const float* __restrict__ vw, const float* __restrict__ pw,
    __bf16* __restrict__ wb,
    const float* __restrict__ x, float2* __restrict__ psum)
{
  if (blockIdx.x < 1024) {
    int idx = blockIdx.x * 256 + threadIdx.x;
    int mat = idx >> 16;
    int off = (idx & 65535) * 4;
    const float* src = (mat == 0) ? qw : (mat == 1) ? kw : (mat == 2) ? vw : pw;
    float4 v = *(const float4*)(src + off);
    bf16x4_t pk;
    pk[0] = f2b(v.x); pk[1] = f2b(v.y); pk[2] = f2b(v.z); pk[3] = f2b(v.w);
    *(bf16x4_t*)(wb + mat * (512 * 512) + off) = pk;
  } else {
    const int t = blockIdx.x - 1024;
    const int s = t & 7, bg = t >> 3;
    const float* xp = x + ((size_t)bg * CG + s * 8) * N_PIX;
    float sum = 0.f, sum2 = 0.f;
#pragma unroll
    for (int it = 0; it < 8; it++) {
      float4 v = ((const float4*)xp)[it * 256 + threadIdx.x];
      sum  += v.x + v.y + v.z + v.w;
      sum2 += v.x * v.x + v.y * v.y + v.z * v.z + v.w * v.w;
    }
#pragma unroll
    for (int off = 32; off; off >>= 1) {
      sum  += __shfl_xor(sum, off, 64);
      sum2 += __shfl_xor(sum2, off, 64);
    }
    __shared__ float red[8];
    const int lane = threadIdx.x & 63, wv = threadIdx.x >> 6;
    if (lane == 0) { red[wv] = sum; red[4 + wv] = sum2; }
    __syncthreads();
    if (threadIdx.x == 0) {
      float s1 = red[0] + red[1] + red[2] + red[3];
      float s2 = red[4] + red[5] + red[6] + red[7];
      psum[bg * 8 + s] = make_float2(s1, s2);
    }
  }
}

// ---------------- GroupNorm apply + transpose -> xnT bf16 [B][N][C] ----------------
__global__ __launch_bounds__(256) void gn_apply_kernel(
    const float* __restrict__ x, const float2* __restrict__ psum,
    const float* __restrict__ gw, const float* __restrict__ gb,
    __bf16* __restrict__ xnT)
{
  const int n0 = blockIdx.x * 32, b = blockIdx.y;
  const int tid = threadIdx.x;
  __shared__ float mu_s[8], rs_s[8];
  __shared__ __align__(16) __bf16 tile[32 * 520];

  if (tid < 8) {
    float s1 = 0.f, s2 = 0.f;
#pragma unroll
    for (int i = 0; i < 8; i++) {
      float2 p = psum[(b * 8 + tid) * 8 + i];
      s1 += p.x; s2 += p.y;
    }
    const float inv = 1.f / (float)(CG * N_PIX);
    float mu = s1 * inv;
    float var = s2 * inv - mu * mu;
    mu_s[tid] = mu;
    rs_s[tid] = rsqrtf(var + EPSF);
  }
  __syncthreads();

  const float* xb = x + (size_t)b * C_DIM * N_PIX + n0;
  const int cl = tid >> 3;
  const int nq = (tid & 7) * 4;
#pragma unroll
  for (int co = 0; co < 16; co++) {
    const int c = co * 32 + cl;
    float4 v = *(const float4*)(xb + (size_t)c * N_PIX + nq);
    const int g = c >> 6;
    const float rs = rs_s[g];
    const float a = rs * gw[c];
    const float bb = gb[c] - mu_s[g] * a;
    tile[(nq + 0) * 520 + c] = f2b(v.x * a + bb);
    tile[(nq + 1) * 520 + c] = f2b(v.y * a + bb);
    tile[(nq + 2) * 520 + c] = f2b(v.z * a + bb);
    tile[(nq + 3) * 520 + c] = f2b(v.w * a + bb);
  }
  __syncthreads();

  __bf16* dst = xnT + ((size_t)b * N_PIX + n0) * C_DIM;
  const int l32 = tid & 31, nr = tid >> 5;
#pragma unroll
  for (int no = 0; no < 4; no++) {
    const int n = no * 8 + nr;
#pragma unroll
    for (int co = 0; co < 2; co++) {
      const int c = co * 256 + l32 * 8;
      *(bf16x8_t*)(dst + (size_t)n * C_DIM + c) =
          *(const bf16x8_t*)(tile + n * 520 + c);
    }
  }
}

// ---------------- 64x128 gemm_bt core, BK=64 as two 32-col panels (K=512) ----------------
// As: panel p at p*2048, 64x32 row-major. Bs: panel p at p*4096, 128x32 row-major.
// Wave (wv): wm=(wv>>1)*32 rows, wn=(wv&1)*64 cols -> acc[2][4].
__device__ __forceinline__ void gemm_core_64(
    const __bf16* __restrict__ A, const __bf16* __restrict__ B,
    __bf16* As, __bf16* Bs, f32x4_t acc[2][4])
{
  const int tid  = threadIdx.x;
  const int lane = tid & 63;
  const int wv   = tid >> 6;
  const int quad = lane >> 4;
  const int l16  = lane & 15;
  const int wm = (wv >> 1) * 32;
  const int wn = (wv & 1) * 64;

  f32x4_t zero = {0.f, 0.f, 0.f, 0.f};
#pragma unroll
  for (int i = 0; i < 2; i++)
#pragma unroll
    for (int j = 0; j < 4; j++) acc[i][j] = zero;

  // A panel: 256 chunks of 8 elems -> 1 chunk/thread; B panel: 512 -> 2/thread
  const int chA  = wv * 64 + lane;
  const int rA = chA >> 2,  kA = (chA & 3) * 8;
  const int chB0 = wv * 64 + lane, chB1 = 256 + wv * 64 + lane;
  const int rB0 = chB0 >> 2, kB0 = (chB0 & 3) * 8;
  const int rB1 = chB1 >> 2, kB1 = (chB1 & 3) * 8;

  for (int kt = 0; kt < 512; kt += 64) {
#pragma unroll
    for (int p = 0; p < 2; p++) {
      async16(A + (size_t)rA * 512 + kt + p * 32 + kA,  As + p * 2048 + (wv * 64) * 8);
      async16(B + (size_t)rB0 * 512 + kt + p * 32 + kB0, Bs + p * 4096 + (wv * 64) * 8);
      async16(B + (size_t)rB1 * 512 + kt + p * 32 + kB1, Bs + p * 4096 + (256 + wv * 64) * 8);
    }
    __builtin_amdgcn_s_waitcnt(0);
    __syncthreads();
#pragma unroll
    for (int p = 0; p < 2; p++) {
      bf16x8_t af[2], bfr[4];
#pragma unroll
      for (int i = 0; i < 2; i++)
        af[i] = *(const bf16x8_t*)(As + p * 2048 + (wm + i * 16 + l16) * 32 + quad * 8);
#pragma unroll
      for (int j = 0; j < 4; j++)
        bfr[j] = *(const bf16x8_t*)(Bs + p * 4096 + (wn + j * 16 + l16) * 32 + quad * 8);
#pragma unroll
      for (int i = 0; i < 2; i++)
#pragma unroll
        for (int j = 0; j < 4; j++)
          acc[i][j] = __builtin_amdgcn_mfma_f32_16x16x32_bf16(af[i], bfr[j], acc[i][j], 0, 0, 0);
    }
    __syncthreads();
  }
}

// ---------------- QKV gemm: 64x128 tiles, grid (8=b, 8=n, 24=mat*8+mz) ----------------
__global__ __launch_bounds__(256, 4) void gemm_qkv_kernel(
    const __bf16* __restrict__ wqkv, const float* __restrict__ qb,
    const float* __restrict__ kb, const float* __restrict__ vb,
    const __bf16* __restrict__ xnT,
    __bf16* __restrict__ qT, __bf16* __restrict__ kT, __bf16* __restrict__ vbuf)
{
  __shared__ __align__(16) __bf16 smem[12288];   // 24 KB: As(4096) | Bs(8192); V-transpose reuse
  __bf16* As = smem;
  __bf16* Bs = smem + 4096;
  const int b = blockIdx.x;
  const int n0 = blockIdx.y * 128;
  const int z = blockIdx.z;
  const int mat = z >> 3;
  const int m0 = (z & 7) * 64;
  const __bf16* A = wqkv + (size_t)mat * (512 * 512) + (size_t)m0 * 512;
  const __bf16* B = xnT + ((size_t)b * N_PIX + n0) * 512;
  f32x4_t acc[2][4];
  gemm_core_64(A, B, As, Bs, acc);

  const int tid = threadIdx.x, lane = tid & 63, wv = tid >> 6;
  const int quad = lane >> 4, l16 = lane & 15;
  const int wm = (wv >> 1) * 32, wn = (wv & 1) * 64;
  const float* bias = (mat == 0) ? qb : (mat == 1) ? kb : vb;
  const float qscale = (mat == 0) ? 0.125f * 1.44269504f : 1.0f;  // HD^-0.5 * log2(e)

  if (mat < 2) {
    __bf16* dst = (mat == 0) ? qT : kT;
#pragma unroll
    for (int i = 0; i < 2; i++) {
      const int o = m0 + wm + i * 16 + quad * 4;
      float b0 = bias[o], b1 = bias[o + 1], b2 = bias[o + 2], b3 = bias[o + 3];
#pragma unroll
      for (int j = 0; j < 4; j++) {
        const int n = n0 + wn + j * 16 + l16;
        bf16x4_t pk;
        pk[0] = f2b((acc[i][j][0] + b0) * qscale);
        pk[1] = f2b((acc[i][j][1] + b1) * qscale);
        pk[2] = f2b((acc[i][j][2] + b2) * qscale);
        pk[3] = f2b((acc[i][j][3] + b3) * qscale);
        *(bf16x4_t*)(dst + ((size_t)b * N_PIX + n) * 512 + o) = pk;
      }
    }
  } else {
    // single-pass LDS transpose (64 c-rows x 128 n-cols, stride 132)
#pragma unroll
    for (int i = 0; i < 2; i++) {
      const int crow = wm + i * 16 + quad * 4;
      const int o = m0 + crow;
      float b0 = bias[o], b1 = bias[o + 1], b2 = bias[o + 2], b3 = bias[o + 3];
#pragma unroll
      for (int j = 0; j < 4; j++) {
        const int nl = wn + j * 16 + l16;
        smem[(crow + 0) * 132 + nl] = f2b(acc[i][j][0] + b0);
        smem[(crow + 1) * 132 + nl] = f2b(acc[i][j][1] + b1);
        smem[(crow + 2) * 132 + nl] = f2b(acc[i][j][2] + b2);
        smem[(crow + 3) * 132 + nl] = f2b(acc[i][j][3] + b3);
      }
    }
    __syncthreads();
    const int c = tid >> 2;                 // 0..63
    const int nch = (tid & 3) * 32;
    __bf16* vd = vbuf + ((size_t)b * 512 + m0 + c) * N_PIX + n0 + nch;
#pragma unroll
    for (int k = 0; k < 4; k++)
      *(bf16x8_t*)(vd + k * 8) = *(const bf16x8_t*)(smem + c * 132 + nch + k * 8);
  }
}

// ---------------- attention: 32 q/wave, permuted V, double-buffered (1 barrier/iter) ----------------
__global__ __launch_bounds__(256, 2) void attn_kernel(
    const __bf16* __restrict__ qT, const __bf16* __restrict__ kT,
    const __bf16* __restrict__ vbuf, __bf16* __restrict__ aT)
{
  __shared__ __align__(16) __bf16 Ks[2][64 * 72];
  __shared__ __align__(16) __bf16 Vp[2][64 * 72];
  const int bh = blockIdx.x;
  const int b = bh >> 3, head = bh & 7;
  const int n0 = blockIdx.y * 128;
  const int tid = threadIdx.x, lane = tid & 63, wv = tid >> 6;
  const int quad = lane >> 4, l16 = lane & 15;

  bf16x8_t qf[2][2];
#pragma unroll
  for (int qt = 0; qt < 2; qt++) {
    const __bf16* qp = qT + ((size_t)b * N_PIX + n0 + wv * 32 + qt * 16 + l16) * 512 + head * 64;
    qf[qt][0] = *(const bf16x8_t*)(qp + quad * 8);
    qf[qt][1] = *(const bf16x8_t*)(qp + 32 + quad * 8);
  }

  const __bf16* kp = kT + ((size_t)b * N_PIX) * 512 + head * 64;
  const __bf16* vp = vbuf + ((size_t)b * 512 + head * 64) * N_PIX;

  const int srow = tid >> 2, scol = (tid & 3) * 16;
  const int pr0 = scol >> 5, hh0 = (scol >> 4) & 1;
  const int pos0 = pr0 * 32 + ((scol >> 2) & 3) * 8 + hh0 * 4;
  const int mc1 = scol + 8;
  const int pr1 = mc1 >> 5, hh1 = (mc1 >> 4) & 1;
  const int pos1 = pr1 * 32 + ((mc1 >> 2) & 3) * 8 + hh1 * 4;

  bf16x8_t kreg0 = *(const bf16x8_t*)(kp + (size_t)srow * 512 + scol);
  bf16x8_t kreg1 = *(const bf16x8_t*)(kp + (size_t)srow * 512 + scol + 8);
  bf16x8_t vreg0 = *(const bf16x8_t*)(vp + (size_t)srow * N_PIX + scol);
  bf16x8_t vreg1 = *(const bf16x8_t*)(vp + (size_t)srow * N_PIX + scol + 8);
  {
    *(bf16x8_t*)(Ks[0] + srow * 72 + scol)     = kreg0;
    *(bf16x8_t*)(Ks[0] + srow * 72 + scol + 8) = kreg1;
    bf16x4_t lo, hi;
#pragma unroll
    for (int r = 0; r < 4; r++) { lo[r] = vreg0[r]; hi[r] = vreg0[4 + r]; }
    *(bf16x4_t*)(Vp[0] + srow * 72 + pos0)     = lo;
    *(bf16x4_t*)(Vp[0] + srow * 72 + pos0 + 8) = hi;
#pragma unroll
    for (int r = 0; r < 4; r++) { lo[r] = vreg1[r]; hi[r] = vreg1[4 + r]; }
    *(bf16x4_t*)(Vp[0] + srow * 72 + pos1)     = lo;
    *(bf16x4_t*)(Vp[0] + srow * 72 + pos1 + 8) = hi;
  }
  kreg0 = *(const bf16x8_t*)(kp + (size_t)(64 + srow) * 512 + scol);
  kreg1 = *(const bf16x8_t*)(kp + (size_t)(64 + srow) * 512 + scol + 8);
  vreg0 = *(const bf16x8_t*)(vp + (size_t)srow * N_PIX + 64 + scol);
  vreg1 = *(const bf16x8_t*)(vp + (size_t)srow * N_PIX + 64 + scol + 8);
  __syncthreads();

  const f32x4_t zero = {0.f, 0.f, 0.f, 0.f};
  f32x4_t oacc[2][4];
#pragma unroll
  for (int qt = 0; qt < 2; qt++)
#pragma unroll
    for (int jc = 0; jc < 4; jc++) oacc[qt][jc] = zero;
  f32x4_t lsum4[2] = {zero, zero};

  for (int mt = 0; mt < 16; mt++) {
    const int cur = mt & 1, nxt = cur ^ 1;
    const __bf16* Kc = Ks[cur];
    const __bf16* Vc = Vp[cur];

    f32x4_t sacc[2][4];
#pragma unroll
    for (int mb = 0; mb < 4; mb++) {
      bf16x8_t kf0 = *(const bf16x8_t*)(Kc + (mb * 16 + l16) * 72 + quad * 8);
      bf16x8_t kf1 = *(const bf16x8_t*)(Kc + (mb * 16 + l16) * 72 + 32 + quad * 8);
#pragma unroll
      for (int qt = 0; qt < 2; qt++) {
        f32x4_t s = zero;
        s = __builtin_amdgcn_mfma_f32_16x16x32_bf16(kf0, qf[qt][0], s, 0, 0, 0);
        s = __builtin_amdgcn_mfma_f32_16x16x32_bf16(kf1, qf[qt][1], s, 0, 0, 0);
        sacc[qt][mb] = s;
      }
    }

    bf16x8_t pf[2][2];
#pragma unroll
    for (int qt = 0; qt < 2; qt++) {
      float p[4][4];
#pragma unroll
      for (int mb = 0; mb < 4; mb++)
#pragma unroll
        for (int r = 0; r < 4; r++) {
          p[mb][r] = __builtin_amdgcn_exp2f(sacc[qt][mb][r]);
          lsum4[qt][r] += p[mb][r];
        }
#pragma unroll
      for (int pr = 0; pr < 2; pr++) {
        u32x4_t u;
        u[0] = pack_trunc(p[2 * pr][0],     p[2 * pr][1]);
        u[1] = pack_trunc(p[2 * pr][2],     p[2 * pr][3]);
        u[2] = pack_trunc(p[2 * pr + 1][0], p[2 * pr + 1][1]);
        u[3] = pack_trunc(p[2 * pr + 1][2], p[2 * pr + 1][3]);
        pf[qt][pr] = __builtin_bit_cast(bf16x8_t, u);
      }
    }

#pragma unroll
    for (int jc = 0; jc < 4; jc++) {
      const int vrow = (jc * 16 + l16) * 72;
#pragma unroll
      for (int pr = 0; pr < 2; pr++) {
        bf16x8_t vf = *(const bf16x8_t*)(Vc + vrow + pr * 32 + quad * 8);
#pragma unroll
        for (int qt = 0; qt < 2; qt++)
          oacc[qt][jc] = __builtin_amdgcn_mfma_f32_16x16x32_bf16(vf, pf[qt][pr], oacc[qt][jc], 0, 0, 0);
      }
    }

    if (mt < 15) {
      *(bf16x8_t*)(Ks[nxt] + srow * 72 + scol)     = kreg0;
      *(bf16x8_t*)(Ks[nxt] + srow * 72 + scol + 8) = kreg1;
      bf16x4_t lo, hi;
#pragma unroll
      for (int r = 0; r < 4; r++) { lo[r] = vreg0[r]; hi[r] = vreg0[4 + r]; }
      *(bf16x4_t*)(Vp[nxt] + srow * 72 + pos0)     = lo;
      *(bf16x4_t*)(Vp[nxt] + srow * 72 + pos0 + 8) = hi;
#pragma unroll
      for (int r = 0; r < 4; r++) { lo[r] = vreg1[r]; hi[r] = vreg1[4 + r]; }
      *(bf16x4_t*)(Vp[nxt] + srow * 72 + pos1)     = lo;
      *(bf16x4_t*)(Vp[nxt] + srow * 72 + pos1 + 8) = hi;
      if (mt < 14) {
        kreg0 = *(const bf16x8_t*)(kp + (size_t)((mt + 2) * 64 + srow) * 512 + scol);
        kreg1 = *(const bf16x8_t*)(kp + (size_t)((mt + 2) * 64 + srow) * 512 + scol + 8);
        vreg0 = *(const bf16x8_t*)(vp + (size_t)srow * N_PIX + (mt + 2) * 64 + scol);
        vreg1 = *(const bf16x8_t*)(vp + (size_t)srow * N_PIX + (mt + 2) * 64 + scol + 8);
      }
      __syncthreads();
    }
  }

#pragma unroll
  for (int qt = 0; qt < 2; qt++) {
    float lsum = lsum4[qt][0] + lsum4[qt][1] + lsum4[qt][2] + lsum4[qt][3];
    lsum += __shfl_xor(lsum, 16, 64);
    lsum += __shfl_xor(lsum, 32, 64);
    const float inv = 1.f / lsum;
    __bf16* op = aT + ((size_t)b * N_PIX + n0 + wv * 32 + qt * 16 + l16) * 512 + head * 64;
#pragma unroll
    for (int jc = 0; jc < 4; jc++) {
      bf16x4_t o4;
#pragma unroll
      for (int r = 0; r < 4; r++) o4[r] = f2b(oacc[qt][jc][r] * inv);
      *(bf16x4_t*)(op + jc * 16 + quad * 4) = o4;
    }
  }
}

// ---------------- proj gemm + bias + residual: 64x128 tiles, grid (8=b, 8=n, 8=m) ----------------
__global__ __launch_bounds__(256, 4) void gemm_proj_kernel(
    const __bf16* __restrict__ wp, const float* __restrict__ pb,
    const __bf16* __restrict__ aT, const float* __restrict__ x,
    float* __restrict__ out)
{
  __shared__ __align__(16) __bf16 smem[12288];
  __bf16* As = smem;
  __bf16* Bs = smem + 4096;
  const int b = blockIdx.x;
  const int n0 = blockIdx.y * 128;
  const int m0 = blockIdx.z * 64;
  const __bf16* A = wp + (size_t)m0 * 512;
  const __bf16* B = aT + ((size_t)b * N_PIX + n0) * 512;
  f32x4_t acc[2][4];
  gemm_core_64(A, B, As, Bs, acc);
  const int tid = threadIdx.x, lane = tid & 63, wv = tid >> 6;
  const int quad = lane >> 4, l16 = lane & 15;
  const int wm = (wv >> 1) * 32, wn = (wv & 1) * 64;
#pragma unroll
  for (int i = 0; i < 2; i++) {
    const int o = m0 + wm + i * 16 + quad * 4;
#pragma unroll
    for (int j = 0; j < 4; j++) {
      const int n = n0 + wn + j * 16 + l16;
#pragma unroll
      for (int r = 0; r < 4; r++) {
        size_t idx = ((size_t)b * 512 + o + r) * N_PIX + n;
        out[idx] = acc[i][j][r] + pb[o + r] + x[idx];
      }
    }
  }
}

extern "C" void kernel_launch(void* const* d_in, const int* in_sizes, int n_in,
                              void* d_out, int out_size, void* d_ws, size_t ws_size,
                              hipStream_t stream)
{
  (void)in_sizes; (void)n_in; (void)out_size; (void)ws_size;
  const float* x   = (const float*)d_in[0];
  const float* gnw = (const float*)d_in[1];
  const float* gnb = (const float*)d_in[2];
  const float* qw  = (const float*)d_in[3];
  const float* qb  = (const float*)d_in[4];
  const float* kw  = (const float*)d_in[5];
  const float* kb  = (const float*)d_in[6];
  const float* vw  = (const float*)d_in[7];
  const float* vb  = (const float*)d_in[8];
  const float* pw  = (const float*)d_in[9];
  const float* pb  = (const float*)d_in[10];
  float* out = (float*)d_out;

  char* ws = (char*)d_ws;
  __bf16* wb   = (__bf16*)(ws);                         // 2 MB
  __bf16* xnT  = (__bf16*)(ws + (size_t)(2  << 20));    // 8 MB
  __bf16* qTb  = (__bf16*)(ws + (size_t)(10 << 20));    // 8 MB
  __bf16* kTb  = (__bf16*)(ws + (size_t)(18 << 20));    // 8 MB
  __bf16* vbf  = (__bf16*)(ws + (size_t)(26 << 20));    // 8 MB
  __bf16* aT   = (__bf16*)(ws + (size_t)(34 << 20));    // 8 MB
  float2* psum = (float2*)(ws + (size_t)(42 << 20));    // 4 KB

  hipLaunchKernelGGL(prep_kernel, dim3(1536), dim3(256), 0, stream,
                     qw, kw, vw, pw, wb, x, psum);
  hipLaunchKernelGGL(gn_apply_kernel, dim3(32, 8), dim3(256), 0, stream, x, psum, gnw, gnb, xnT);
  hipLaunchKernelGGL(gemm_qkv_kernel, dim3(8, 8, 24), dim3(256), 0, stream,
                     wb, qb, kb, vb, xnT, qTb, kTb, vbf);
  hipLaunchKernelGGL(attn_kernel, dim3(64, 8), dim3(256), 0, stream, qTb, kTb, vbf, aT);
  hipLaunchKernelGGL(gemm_proj_kernel, dim3(8, 8, 8), dim3(256), 0, stream,
                     wb + (size_t)3 * 512 * 512, pb, aT, x, out);
}

// Round 11
// 150.813 us; speedup vs baseline: 1.6235x; 1.0193x over previous
//
#include <hip/hip_runtime.h>

#define C_DIM 512
#define N_PIX 1024
#define B_DIM 8
#define NHEAD 8
#define HDIM 64
#define NGRP 8
#define CG 64
#define EPSF 1e-5f

typedef __bf16 bf16x8_t __attribute__((ext_vector_type(8)));
typedef __bf16 bf16x4_t __attribute__((ext_vector_type(4)));
typedef float  f32x4_t  __attribute__((ext_vector_type(4)));
typedef unsigned int u32x4_t __attribute__((ext_vector_type(4)));

__device__ __forceinline__ __bf16 f2b(float f) {
  unsigned int u = __builtin_bit_cast(unsigned int, f);
  u += 0x7fffu + ((u >> 16) & 1u);
  unsigned short s = (unsigned short)(u >> 16);
  return __builtin_bit_cast(__bf16, s);
}

// truncating pack: two fp32 -> packed bf16 pair (low=a, high=b); P>=0 so safe
__device__ __forceinline__ unsigned int pack_trunc(float a, float b) {
  return (__builtin_bit_cast(unsigned int, a) >> 16) |
         (__builtin_bit_cast(unsigned int, b) & 0xffff0000u);
}

__device__ __forceinline__ void async16(const void* g, void* l) {
  __builtin_amdgcn_global_load_lds((const __attribute__((address_space(1))) void*)g,
                                   (__attribute__((address_space(3))) void*)l, 16, 0, 0);
}

// ---------------- prep: weight fp32->bf16 (blocks 0..1023) + GN stats (1024..1535) ----------------
__global__ __launch_bounds__(256) void prep_kernel(
    const float* __restrict__ qw, const float* __restrict__ kw,
    const float* __restrict__ vw, const float* __restrict__ pw,
    __bf16* __restrict__ wb,
    const float* __restrict__ x, float2* __restrict__ psum)
{
  if (blockIdx.x < 1024) {
    int idx = blockIdx.x * 256 + threadIdx.x;
    int mat = idx >> 16;
    int off = (idx & 65535) * 4;
    const float* src = (mat == 0) ? qw : (mat == 1) ? kw : (mat == 2) ? vw : pw;
    float4 v = *(const float4*)(src + off);
    bf16x4_t pk;
    pk[0] = f2b(v.x); pk[1] = f2b(v.y); pk[2] = f2b(v.z); pk[3] = f2b(v.w);
    *(bf16x4_t*)(wb + mat * (512 * 512) + off) = pk;
  } else {
    const int t = blockIdx.x - 1024;
    const int s = t & 7, bg = t >> 3;
    const float* xp = x + ((size_t)bg * CG + s * 8) * N_PIX;
    float sum = 0.f, sum2 = 0.f;
#pragma unroll
    for (int it = 0; it < 8; it++) {
      float4 v = ((const float4*)xp)[it * 256 + threadIdx.x];
      sum  += v.x + v.y + v.z + v.w;
      sum2 += v.x * v.x + v.y * v.y + v.z * v.z + v.w * v.w;
    }
#pragma unroll
    for (int off = 32; off; off >>= 1) {
      sum  += __shfl_xor(sum, off, 64);
      sum2 += __shfl_xor(sum2, off, 64);
    }
    __shared__ float red[8];
    const int lane = threadIdx.x & 63, wv = threadIdx.x >> 6;
    if (lane == 0) { red[wv] = sum; red[4 + wv] = sum2; }
    __syncthreads();
    if (threadIdx.x == 0) {
      float s1 = red[0] + red[1] + red[2] + red[3];
      float s2 = red[4] + red[5] + red[6] + red[7];
      psum[bg * 8 + s] = make_float2(s1, s2);
    }
  }
}

// ---------------- GroupNorm apply + transpose -> xnT bf16 [B][N][C] ----------------
__global__ __launch_bounds__(256) void gn_apply_kernel(
    const float* __restrict__ x, const float2* __restrict__ psum,
    const float* __restrict__ gw, const float* __restrict__ gb,
    __bf16* __restrict__ xnT)
{
  const int n0 = blockIdx.x * 32, b = blockIdx.y;
  const int tid = threadIdx.x;
  __shared__ float mu_s[8], rs_s[8];
  __shared__ __align__(16) __bf16 tile[32 * 520];

  if (tid < 8) {
    float s1 = 0.f, s2 = 0.f;
#pragma unroll
    for (int i = 0; i < 8; i++) {
      float2 p = psum[(b * 8 + tid) * 8 + i];
      s1 += p.x; s2 += p.y;
    }
    const float inv = 1.f / (float)(CG * N_PIX);
    float mu = s1 * inv;
    float var = s2 * inv - mu * mu;
    mu_s[tid] = mu;
    rs_s[tid] = rsqrtf(var + EPSF);
  }
  __syncthreads();

  const float* xb = x + (size_t)b * C_DIM * N_PIX + n0;
  const int cl = tid >> 3;
  const int nq = (tid & 7) * 4;
#pragma unroll
  for (int co = 0; co < 16; co++) {
    const int c = co * 32 + cl;
    float4 v = *(const float4*)(xb + (size_t)c * N_PIX + nq);
    const int g = c >> 6;
    const float rs = rs_s[g];
    const float a = rs * gw[c];
    const float bb = gb[c] - mu_s[g] * a;
    tile[(nq + 0) * 520 + c] = f2b(v.x * a + bb);
    tile[(nq + 1) * 520 + c] = f2b(v.y * a + bb);
    tile[(nq + 2) * 520 + c] = f2b(v.z * a + bb);
    tile[(nq + 3) * 520 + c] = f2b(v.w * a + bb);
  }
  __syncthreads();

  __bf16* dst = xnT + ((size_t)b * N_PIX + n0) * C_DIM;
  const int l32 = tid & 31, nr = tid >> 5;
#pragma unroll
  for (int no = 0; no < 4; no++) {
    const int n = no * 8 + nr;
#pragma unroll
    for (int co = 0; co < 2; co++) {
      const int c = co * 256 + l32 * 8;
      *(bf16x8_t*)(dst + (size_t)n * C_DIM + c) =
          *(const bf16x8_t*)(tile + n * 520 + c);
    }
  }
}

// ---------------- 64x128 gemm_bt core, BK=64 as two 32-col panels (K=512) ----------------
__device__ __forceinline__ void gemm_core_64(
    const __bf16* __restrict__ A, const __bf16* __restrict__ B,
    __bf16* As, __bf16* Bs, f32x4_t acc[2][4])
{
  const int tid  = threadIdx.x;
  const int lane = tid & 63;
  const int wv   = tid >> 6;
  const int quad = lane >> 4;
  const int l16  = lane & 15;
  const int wm = (wv >> 1) * 32;
  const int wn = (wv & 1) * 64;

  f32x4_t zero = {0.f, 0.f, 0.f, 0.f};
#pragma unroll
  for (int i = 0; i < 2; i++)
#pragma unroll
    for (int j = 0; j < 4; j++) acc[i][j] = zero;

  const int chA  = wv * 64 + lane;
  const int rA = chA >> 2,  kA = (chA & 3) * 8;
  const int chB0 = wv * 64 + lane, chB1 = 256 + wv * 64 + lane;
  const int rB0 = chB0 >> 2, kB0 = (chB0 & 3) * 8;
  const int rB1 = chB1 >> 2, kB1 = (chB1 & 3) * 8;

  for (int kt = 0; kt < 512; kt += 64) {
#pragma unroll
    for (int p = 0; p < 2; p++) {
      async16(A + (size_t)rA * 512 + kt + p * 32 + kA,  As + p * 2048 + (wv * 64) * 8);
      async16(B + (size_t)rB0 * 512 + kt + p * 32 + kB0, Bs + p * 4096 + (wv * 64) * 8);
      async16(B + (size_t)rB1 * 512 + kt + p * 32 + kB1, Bs + p * 4096 + (256 + wv * 64) * 8);
    }
    __builtin_amdgcn_s_waitcnt(0);
    __syncthreads();
#pragma unroll
    for (int p = 0; p < 2; p++) {
      bf16x8_t af[2], bfr[4];
#pragma unroll
      for (int i = 0; i < 2; i++)
        af[i] = *(const bf16x8_t*)(As + p * 2048 + (wm + i * 16 + l16) * 32 + quad * 8);
#pragma unroll
      for (int j = 0; j < 4; j++)
        bfr[j] = *(const bf16x8_t*)(Bs + p * 4096 + (wn + j * 16 + l16) * 32 + quad * 8);
#pragma unroll
      for (int i = 0; i < 2; i++)
#pragma unroll
        for (int j = 0; j < 4; j++)
          acc[i][j] = __builtin_amdgcn_mfma_f32_16x16x32_bf16(af[i], bfr[j], acc[i][j], 0, 0, 0);
    }
    __syncthreads();
  }
}

// ---------------- QKV gemm: 64x128 tiles, grid (8=b, 8=n, 24=mat*8+mz) ----------------
// ALL epilogues now go through LDS transpose -> coalesced 16B/lane stores.
__global__ __launch_bounds__(256, 4) void gemm_qkv_kernel(
    const __bf16* __restrict__ wqkv, const float* __restrict__ qb,
    const float* __restrict__ kb, const float* __restrict__ vb,
    const __bf16* __restrict__ xnT,
    __bf16* __restrict__ qT, __bf16* __restrict__ kT, __bf16* __restrict__ vbuf)
{
  __shared__ __align__(16) __bf16 smem[12288];   // 24 KB: As(4096)|Bs(8192); epilogue reuse
  __bf16* As = smem;
  __bf16* Bs = smem + 4096;
  const int b = blockIdx.x;
  const int n0 = blockIdx.y * 128;
  const int z = blockIdx.z;
  const int mat = z >> 3;
  const int m0 = (z & 7) * 64;
  const __bf16* A = wqkv + (size_t)mat * (512 * 512) + (size_t)m0 * 512;
  const __bf16* B = xnT + ((size_t)b * N_PIX + n0) * 512;
  f32x4_t acc[2][4];
  gemm_core_64(A, B, As, Bs, acc);

  const int tid = threadIdx.x, lane = tid & 63, wv = tid >> 6;
  const int quad = lane >> 4, l16 = lane & 15;
  const int wm = (wv >> 1) * 32, wn = (wv & 1) * 64;
  const float* bias = (mat == 0) ? qb : (mat == 1) ? kb : vb;
  const float qscale = (mat == 0) ? 0.125f * 1.44269504f : 1.0f;  // HD^-0.5 * log2(e)

  if (mat < 2) {
    __bf16* dst = (mat == 0) ? qT : kT;
    // transpose through LDS: Tr[n][c] stride 72 (2-way write conflicts = free)
#pragma unroll
    for (int i = 0; i < 2; i++) {
      const int crow = wm + i * 16 + quad * 4;
      const int o = m0 + crow;
      float b0 = bias[o], b1 = bias[o + 1], b2 = bias[o + 2], b3 = bias[o + 3];
#pragma unroll
      for (int j = 0; j < 4; j++) {
        const int nl = wn + j * 16 + l16;
        bf16x4_t pk;
        pk[0] = f2b((acc[i][j][0] + b0) * qscale);
        pk[1] = f2b((acc[i][j][1] + b1) * qscale);
        pk[2] = f2b((acc[i][j][2] + b2) * qscale);
        pk[3] = f2b((acc[i][j][3] + b3) * qscale);
        *(bf16x4_t*)(smem + nl * 72 + crow) = pk;
      }
    }
    __syncthreads();
    // coalesced out: 8 lanes cover a full 128B (64-channel) run per n
#pragma unroll
    for (int it = 0; it < 4; it++) {
      const int n = it * 32 + (tid >> 3);
      const int c = (tid & 7) * 8;
      *(bf16x8_t*)(dst + ((size_t)b * N_PIX + n0 + n) * 512 + m0 + c) =
          *(const bf16x8_t*)(smem + n * 72 + c);
    }
  } else {
    // single-pass LDS transpose (64 c-rows x 128 n-cols, stride 132)
#pragma unroll
    for (int i = 0; i < 2; i++) {
      const int crow = wm + i * 16 + quad * 4;
      const int o = m0 + crow;
      float b0 = bias[o], b1 = bias[o + 1], b2 = bias[o + 2], b3 = bias[o + 3];
#pragma unroll
      for (int j = 0; j < 4; j++) {
        const int nl = wn + j * 16 + l16;
        smem[(crow + 0) * 132 + nl] = f2b(acc[i][j][0] + b0);
        smem[(crow + 1) * 132 + nl] = f2b(acc[i][j][1] + b1);
        smem[(crow + 2) * 132 + nl] = f2b(acc[i][j][2] + b2);
        smem[(crow + 3) * 132 + nl] = f2b(acc[i][j][3] + b3);
      }
    }
    __syncthreads();
    const int c = tid >> 2;                 // 0..63
    const int nch = (tid & 3) * 32;
    __bf16* vd = vbuf + ((size_t)b * 512 + m0 + c) * N_PIX + n0 + nch;
#pragma unroll
    for (int k = 0; k < 4; k++)
      *(bf16x8_t*)(vd + k * 8) = *(const bf16x8_t*)(smem + c * 132 + nch + k * 8);
  }
}

// ---------------- attention: 32 q/wave, permuted V, double-buffered, LDS-transposed out ----------------
__global__ __launch_bounds__(256, 2) void attn_kernel(
    const __bf16* __restrict__ qT, const __bf16* __restrict__ kT,
    const __bf16* __restrict__ vbuf, __bf16* __restrict__ aT)
{
  __shared__ __align__(16) __bf16 Ks[2][64 * 72];
  __shared__ __align__(16) __bf16 Vp[2][64 * 72];
  const int bh = blockIdx.x;
  const int b = bh >> 3, head = bh & 7;
  const int n0 = blockIdx.y * 128;
  const int tid = threadIdx.x, lane = tid & 63, wv = tid >> 6;
  const int quad = lane >> 4, l16 = lane & 15;

  bf16x8_t qf[2][2];
#pragma unroll
  for (int qt = 0; qt < 2; qt++) {
    const __bf16* qp = qT + ((size_t)b * N_PIX + n0 + wv * 32 + qt * 16 + l16) * 512 + head * 64;
    qf[qt][0] = *(const bf16x8_t*)(qp + quad * 8);
    qf[qt][1] = *(const bf16x8_t*)(qp + 32 + quad * 8);
  }

  const __bf16* kp = kT + ((size_t)b * N_PIX) * 512 + head * 64;
  const __bf16* vp = vbuf + ((size_t)b * 512 + head * 64) * N_PIX;

  const int srow = tid >> 2, scol = (tid & 3) * 16;
  const int pr0 = scol >> 5, hh0 = (scol >> 4) & 1;
  const int pos0 = pr0 * 32 + ((scol >> 2) & 3) * 8 + hh0 * 4;
  const int mc1 = scol + 8;
  const int pr1 = mc1 >> 5, hh1 = (mc1 >> 4) & 1;
  const int pos1 = pr1 * 32 + ((mc1 >> 2) & 3) * 8 + hh1 * 4;

  bf16x8_t kreg0 = *(const bf16x8_t*)(kp + (size_t)srow * 512 + scol);
  bf16x8_t kreg1 = *(const bf16x8_t*)(kp + (size_t)srow * 512 + scol + 8);
  bf16x8_t vreg0 = *(const bf16x8_t*)(vp + (size_t)srow * N_PIX + scol);
  bf16x8_t vreg1 = *(const bf16x8_t*)(vp + (size_t)srow * N_PIX + scol + 8);
  {
    *(bf16x8_t*)(Ks[0] + srow * 72 + scol)     = kreg0;
    *(bf16x8_t*)(Ks[0] + srow * 72 + scol + 8) = kreg1;
    bf16x4_t lo, hi;
#pragma unroll
    for (int r = 0; r < 4; r++) { lo[r] = vreg0[r]; hi[r] = vreg0[4 + r]; }
    *(bf16x4_t*)(Vp[0] + srow * 72 + pos0)     = lo;
    *(bf16x4_t*)(Vp[0] + srow * 72 + pos0 + 8) = hi;
#pragma unroll
    for (int r = 0; r < 4; r++) { lo[r] = vreg1[r]; hi[r] = vreg1[4 + r]; }
    *(bf16x4_t*)(Vp[0] + srow * 72 + pos1)     = lo;
    *(bf16x4_t*)(Vp[0] + srow * 72 + pos1 + 8) = hi;
  }
  kreg0 = *(const bf16x8_t*)(kp + (size_t)(64 + srow) * 512 + scol);
  kreg1 = *(const bf16x8_t*)(kp + (size_t)(64 + srow) * 512 + scol + 8);
  vreg0 = *(const bf16x8_t*)(vp + (size_t)srow * N_PIX + 64 + scol);
  vreg1 = *(const bf16x8_t*)(vp + (size_t)srow * N_PIX + 64 + scol + 8);
  __syncthreads();

  const f32x4_t zero = {0.f, 0.f, 0.f, 0.f};
  f32x4_t oacc[2][4];
#pragma unroll
  for (int qt = 0; qt < 2; qt++)
#pragma unroll
    for (int jc = 0; jc < 4; jc++) oacc[qt][jc] = zero;
  f32x4_t lsum4[2] = {zero, zero};

  for (int mt = 0; mt < 16; mt++) {
    const int cur = mt & 1, nxt = cur ^ 1;
    const __bf16* Kc = Ks[cur];
    const __bf16* Vc = Vp[cur];

    f32x4_t sacc[2][4];
#pragma unroll
    for (int mb = 0; mb < 4; mb++) {
      bf16x8_t kf0 = *(const bf16x8_t*)(Kc + (mb * 16 + l16) * 72 + quad * 8);
      bf16x8_t kf1 = *(const bf16x8_t*)(Kc + (mb * 16 + l16) * 72 + 32 + quad * 8);
#pragma unroll
      for (int qt = 0; qt < 2; qt++) {
        f32x4_t s = zero;
        s = __builtin_amdgcn_mfma_f32_16x16x32_bf16(kf0, qf[qt][0], s, 0, 0, 0);
        s = __builtin_amdgcn_mfma_f32_16x16x32_bf16(kf1, qf[qt][1], s, 0, 0, 0);
        sacc[qt][mb] = s;
      }
    }

    bf16x8_t pf[2][2];
#pragma unroll
    for (int qt = 0; qt < 2; qt++) {
      float p[4][4];
#pragma unroll
      for (int mb = 0; mb < 4; mb++)
#pragma unroll
        for (int r = 0; r < 4; r++) {
          p[mb][r] = __builtin_amdgcn_exp2f(sacc[qt][mb][r]);
          lsum4[qt][r] += p[mb][r];
        }
#pragma unroll
      for (int pr = 0; pr < 2; pr++) {
        u32x4_t u;
        u[0] = pack_trunc(p[2 * pr][0],     p[2 * pr][1]);
        u[1] = pack_trunc(p[2 * pr][2],     p[2 * pr][3]);
        u[2] = pack_trunc(p[2 * pr + 1][0], p[2 * pr + 1][1]);
        u[3] = pack_trunc(p[2 * pr + 1][2], p[2 * pr + 1][3]);
        pf[qt][pr] = __builtin_bit_cast(bf16x8_t, u);
      }
    }

#pragma unroll
    for (int jc = 0; jc < 4; jc++) {
      const int vrow = (jc * 16 + l16) * 72;
#pragma unroll
      for (int pr = 0; pr < 2; pr++) {
        bf16x8_t vf = *(const bf16x8_t*)(Vc + vrow + pr * 32 + quad * 8);
#pragma unroll
        for (int qt = 0; qt < 2; qt++)
          oacc[qt][jc] = __builtin_amdgcn_mfma_f32_16x16x32_bf16(vf, pf[qt][pr], oacc[qt][jc], 0, 0, 0);
      }
    }

    if (mt < 15) {
      *(bf16x8_t*)(Ks[nxt] + srow * 72 + scol)     = kreg0;
      *(bf16x8_t*)(Ks[nxt] + srow * 72 + scol + 8) = kreg1;
      bf16x4_t lo, hi;
#pragma unroll
      for (int r = 0; r < 4; r++) { lo[r] = vreg0[r]; hi[r] = vreg0[4 + r]; }
      *(bf16x4_t*)(Vp[nxt] + srow * 72 + pos0)     = lo;
      *(bf16x4_t*)(Vp[nxt] + srow * 72 + pos0 + 8) = hi;
#pragma unroll
      for (int r = 0; r < 4; r++) { lo[r] = vreg1[r]; hi[r] = vreg1[4 + r]; }
      *(bf16x4_t*)(Vp[nxt] + srow * 72 + pos1)     = lo;
      *(bf16x4_t*)(Vp[nxt] + srow * 72 + pos1 + 8) = hi;
      if (mt < 14) {
        kreg0 = *(const bf16x8_t*)(kp + (size_t)((mt + 2) * 64 + srow) * 512 + scol);
        kreg1 = *(const bf16x8_t*)(kp + (size_t)((mt + 2) * 64 + srow) * 512 + scol + 8);
        vreg0 = *(const bf16x8_t*)(vp + (size_t)srow * N_PIX + (mt + 2) * 64 + scol);
        vreg1 = *(const bf16x8_t*)(vp + (size_t)srow * N_PIX + (mt + 2) * 64 + scol + 8);
      }
      __syncthreads();
    }
  }

  // O epilogue: normalize, transpose through LDS (reuse Ks = 9216 elems), coalesced stores
  __syncthreads();
  __bf16* Tr = &Ks[0][0];
#pragma unroll
  for (int qt = 0; qt < 2; qt++) {
    float lsum = lsum4[qt][0] + lsum4[qt][1] + lsum4[qt][2] + lsum4[qt][3];
    lsum += __shfl_xor(lsum, 16, 64);
    lsum += __shfl_xor(lsum, 32, 64);
    const float inv = 1.f / lsum;
    const int nl = wv * 32 + qt * 16 + l16;
#pragma unroll
    for (int jc = 0; jc < 4; jc++) {
      bf16x4_t o4;
#pragma unroll
      for (int r = 0; r < 4; r++) o4[r] = f2b(oacc[qt][jc][r] * inv);
      *(bf16x4_t*)(Tr + nl * 72 + jc * 16 + quad * 4) = o4;
    }
  }
  __syncthreads();
#pragma unroll
  for (int it = 0; it < 4; it++) {
    const int n = it * 32 + (tid >> 3);
    const int c = (tid & 7) * 8;
    *(bf16x8_t*)(aT + ((size_t)b * N_PIX + n0 + n) * 512 + head * 64 + c) =
        *(const bf16x8_t*)(Tr + n * 72 + c);
  }
}

// ---------------- proj gemm + bias + residual: 64x128 tiles, grid (8=b, 8=n, 8=m) ----------------
__global__ __launch_bounds__(256, 4) void gemm_proj_kernel(
    const __bf16* __restrict__ wp, const float* __restrict__ pb,
    const __bf16* __restrict__ aT, const float* __restrict__ x,
    float* __restrict__ out)
{
  __shared__ __align__(16) __bf16 smem[12288];
  __bf16* As = smem;
  __bf16* Bs = smem + 4096;
  const int b = blockIdx.x;
  const int n0 = blockIdx.y * 128;
  const int m0 = blockIdx.z * 64;
  const __bf16* A = wp + (size_t)m0 * 512;
  const __bf16* B = aT + ((size_t)b * N_PIX + n0) * 512;
  f32x4_t acc[2][4];
  gemm_core_64(A, B, As, Bs, acc);
  const int tid = threadIdx.x, lane = tid & 63, wv = tid >> 6;
  const int quad = lane >> 4, l16 = lane & 15;
  const int wm = (wv >> 1) * 32, wn = (wv & 1) * 64;
#pragma unroll
  for (int i = 0; i < 2; i++) {
    const int o = m0 + wm + i * 16 + quad * 4;
#pragma unroll
    for (int j = 0; j < 4; j++) {
      const int n = n0 + wn + j * 16 + l16;
#pragma unroll
      for (int r = 0; r < 4; r++) {
        size_t idx = ((size_t)b * 512 + o + r) * N_PIX + n;
        out[idx] = acc[i][j][r] + pb[o + r] + x[idx];
      }
    }
  }
}

extern "C" void kernel_launch(void* const* d_in, const int* in_sizes, int n_in,
                              void* d_out, int out_size, void* d_ws, size_t ws_size,
                              hipStream_t stream)
{
  (void)in_sizes; (void)n_in; (void)out_size; (void)ws_size;
  const float* x   = (const float*)d_in[0];
  const float* gnw = (const float*)d_in[1];
  const float* gnb = (const float*)d_in[2];
  const float* qw  = (const float*)d_in[3];
  const float* qb  = (const float*)d_in[4];
  const float* kw  = (const float*)d_in[5];
  const float* kb  = (const float*)d_in[6];
  const float* vw  = (const float*)d_in[7];
  const float* vb  = (const float*)d_in[8];
  const float* pw  = (const float*)d_in[9];
  const float* pb  = (const float*)d_in[10];
  float* out = (float*)d_out;

  char* ws = (char*)d_ws;
  __bf16* wb   = (__bf16*)(ws);                         // 2 MB
  __bf16* xnT  = (__bf16*)(ws + (size_t)(2  << 20));    // 8 MB
  __bf16* qTb  = (__bf16*)(ws + (size_t)(10 << 20));    // 8 MB
  __bf16* kTb  = (__bf16*)(ws + (size_t)(18 << 20));    // 8 MB
  __bf16* vbf  = (__bf16*)(ws + (size_t)(26 << 20));    // 8 MB
  __bf16* aT   = (__bf16*)(ws + (size_t)(34 << 20));    // 8 MB
  float2* psum = (float2*)(ws + (size_t)(42 << 20));    // 4 KB

  hipLaunchKernelGGL(prep_kernel, dim3(1536), dim3(256), 0, stream,
                     qw, kw, vw, pw, wb, x, psum);
  hipLaunchKernelGGL(gn_apply_kernel, dim3(32, 8), dim3(256), 0, stream, x, psum, gnw, gnb, xnT);
  hipLaunchKernelGGL(gemm_qkv_kernel, dim3(8, 8, 24), dim3(256), 0, stream,
                     wb, qb, kb, vb, xnT, qTb, kTb, vbf);
  hipLaunchKernelGGL(attn_kernel, dim3(64, 8), dim3(256), 0, stream, qTb, kTb, vbf, aT);
  hipLaunchKernelGGL(gemm_proj_kernel, dim3(8, 8, 8), dim3(256), 0, stream,
                     wb + (size_t)3 * 512 * 512, pb, aT, x, out);
}

// Round 12
// 149.494 us; speedup vs baseline: 1.6379x; 1.0088x over previous
//
#include <hip/hip_runtime.h>

#define C_DIM 512
#define N_PIX 1024
#define B_DIM 8
#define NHEAD 8
#define HDIM 64
#define NGRP 8
#define CG 64
#define EPSF 1e-5f

typedef __bf16 bf16x8_t __attribute__((ext_vector_type(8)));
typedef __bf16 bf16x4_t __attribute__((ext_vector_type(4)));
typedef float  f32x4_t  __attribute__((ext_vector_type(4)));
typedef unsigned int u32x4_t __attribute__((ext_vector_type(4)));

__device__ __forceinline__ __bf16 f2b(float f) {
  unsigned int u = __builtin_bit_cast(unsigned int, f);
  u += 0x7fffu + ((u >> 16) & 1u);
  unsigned short s = (unsigned short)(u >> 16);
  return __builtin_bit_cast(__bf16, s);
}

// truncating pack: two fp32 -> packed bf16 pair (low=a, high=b); P>=0 so safe
__device__ __forceinline__ unsigned int pack_trunc(float a, float b) {
  return (__builtin_bit_cast(unsigned int, a) >> 16) |
         (__builtin_bit_cast(unsigned int, b) & 0xffff0000u);
}

__device__ __forceinline__ void async16(const void* g, void* l) {
  __builtin_amdgcn_global_load_lds((const __attribute__((address_space(1))) void*)g,
                                   (__attribute__((address_space(3))) void*)l, 16, 0, 0);
}

// ---------------- prep: weight fp32->bf16 (blocks 0..1023) + GN stats (1024..1535) ----------------
__global__ __launch_bounds__(256) void prep_kernel(
    const float* __restrict__ qw, const float* __restrict__ kw,
    const float* __restrict__ vw, const float* __restrict__ pw,
    __bf16* __restrict__ wb,
    const float* __restrict__ x, float2* __restrict__ psum)
{
  if (blockIdx.x < 1024) {
    int idx = blockIdx.x * 256 + threadIdx.x;
    int mat = idx >> 16;
    int off = (idx & 65535) * 4;
    const float* src = (mat == 0) ? qw : (mat == 1) ? kw : (mat == 2) ? vw : pw;
    float4 v = *(const float4*)(src + off);
    bf16x4_t pk;
    pk[0] = f2b(v.x); pk[1] = f2b(v.y); pk[2] = f2b(v.z); pk[3] = f2b(v.w);
    *(bf16x4_t*)(wb + mat * (512 * 512) + off) = pk;
  } else {
    const int t = blockIdx.x - 1024;
    const int s = t & 7, bg = t >> 3;
    const float* xp = x + ((size_t)bg * CG + s * 8) * N_PIX;
    float sum = 0.f, sum2 = 0.f;
#pragma unroll
    for (int it = 0; it < 8; it++) {
      float4 v = ((const float4*)xp)[it * 256 + threadIdx.x];
      sum  += v.x + v.y + v.z + v.w;
      sum2 += v.x * v.x + v.y * v.y + v.z * v.z + v.w * v.w;
    }
#pragma unroll
    for (int off = 32; off; off >>= 1) {
      sum  += __shfl_xor(sum, off, 64);
      sum2 += __shfl_xor(sum2, off, 64);
    }
    __shared__ float red[8];
    const int lane = threadIdx.x & 63, wv = threadIdx.x >> 6;
    if (lane == 0) { red[wv] = sum; red[4 + wv] = sum2; }
    __syncthreads();
    if (threadIdx.x == 0) {
      float s1 = red[0] + red[1] + red[2] + red[3];
      float s2 = red[4] + red[5] + red[6] + red[7];
      psum[bg * 8 + s] = make_float2(s1, s2);
    }
  }
}

// ---------------- GroupNorm apply + transpose -> xnT bf16 [B][N][C] ----------------
__global__ __launch_bounds__(256) void gn_apply_kernel(
    const float* __restrict__ x, const float2* __restrict__ psum,
    const float* __restrict__ gw, const float* __restrict__ gb,
    __bf16* __restrict__ xnT)
{
  const int n0 = blockIdx.x * 32, b = blockIdx.y;
  const int tid = threadIdx.x;
  __shared__ float mu_s[8], rs_s[8];
  __shared__ __align__(16) __bf16 tile[32 * 520];

  if (tid < 8) {
    float s1 = 0.f, s2 = 0.f;
#pragma unroll
    for (int i = 0; i < 8; i++) {
      float2 p = psum[(b * 8 + tid) * 8 + i];
      s1 += p.x; s2 += p.y;
    }
    const float inv = 1.f / (float)(CG * N_PIX);
    float mu = s1 * inv;
    float var = s2 * inv - mu * mu;
    mu_s[tid] = mu;
    rs_s[tid] = rsqrtf(var + EPSF);
  }
  __syncthreads();

  const float* xb = x + (size_t)b * C_DIM * N_PIX + n0;
  const int cl = tid >> 3;
  const int nq = (tid & 7) * 4;
#pragma unroll
  for (int co = 0; co < 16; co++) {
    const int c = co * 32 + cl;
    float4 v = *(const float4*)(xb + (size_t)c * N_PIX + nq);
    const int g = c >> 6;
    const float rs = rs_s[g];
    const float a = rs * gw[c];
    const float bb = gb[c] - mu_s[g] * a;
    tile[(nq + 0) * 520 + c] = f2b(v.x * a + bb);
    tile[(nq + 1) * 520 + c] = f2b(v.y * a + bb);
    tile[(nq + 2) * 520 + c] = f2b(v.z * a + bb);
    tile[(nq + 3) * 520 + c] = f2b(v.w * a + bb);
  }
  __syncthreads();

  __bf16* dst = xnT + ((size_t)b * N_PIX + n0) * C_DIM;
  const int l32 = tid & 31, nr = tid >> 5;
#pragma unroll
  for (int no = 0; no < 4; no++) {
    const int n = no * 8 + nr;
#pragma unroll
    for (int co = 0; co < 2; co++) {
      const int c = co * 256 + l32 * 8;
      *(bf16x8_t*)(dst + (size_t)n * C_DIM + c) =
          *(const bf16x8_t*)(tile + n * 520 + c);
    }
  }
}

// ---------------- 64x128 gemm_bt core (proj), BK=64 as two 32-col panels ----------------
__device__ __forceinline__ void gemm_core_64(
    const __bf16* __restrict__ A, const __bf16* __restrict__ B,
    __bf16* As, __bf16* Bs, f32x4_t acc[2][4])
{
  const int tid  = threadIdx.x;
  const int lane = tid & 63;
  const int wv   = tid >> 6;
  const int quad = lane >> 4;
  const int l16  = lane & 15;
  const int wm = (wv >> 1) * 32;
  const int wn = (wv & 1) * 64;

  f32x4_t zero = {0.f, 0.f, 0.f, 0.f};
#pragma unroll
  for (int i = 0; i < 2; i++)
#pragma unroll
    for (int j = 0; j < 4; j++) acc[i][j] = zero;

  const int chA  = wv * 64 + lane;
  const int rA = chA >> 2,  kA = (chA & 3) * 8;
  const int chB0 = wv * 64 + lane, chB1 = 256 + wv * 64 + lane;
  const int rB0 = chB0 >> 2, kB0 = (chB0 & 3) * 8;
  const int rB1 = chB1 >> 2, kB1 = (chB1 & 3) * 8;

  for (int kt = 0; kt < 512; kt += 64) {
#pragma unroll
    for (int p = 0; p < 2; p++) {
      async16(A + (size_t)rA * 512 + kt + p * 32 + kA,  As + p * 2048 + (wv * 64) * 8);
      async16(B + (size_t)rB0 * 512 + kt + p * 32 + kB0, Bs + p * 4096 + (wv * 64) * 8);
      async16(B + (size_t)rB1 * 512 + kt + p * 32 + kB1, Bs + p * 4096 + (256 + wv * 64) * 8);
    }
    __builtin_amdgcn_s_waitcnt(0);
    __syncthreads();
#pragma unroll
    for (int p = 0; p < 2; p++) {
      bf16x8_t af[2], bfr[4];
#pragma unroll
      for (int i = 0; i < 2; i++)
        af[i] = *(const bf16x8_t*)(As + p * 2048 + (wm + i * 16 + l16) * 32 + quad * 8);
#pragma unroll
      for (int j = 0; j < 4; j++)
        bfr[j] = *(const bf16x8_t*)(Bs + p * 4096 + (wn + j * 16 + l16) * 32 + quad * 8);
#pragma unroll
      for (int i = 0; i < 2; i++)
#pragma unroll
        for (int j = 0; j < 4; j++)
          acc[i][j] = __builtin_amdgcn_mfma_f32_16x16x32_bf16(af[i], bfr[j], acc[i][j], 0, 0, 0);
    }
    __syncthreads();
  }
}

// ---------------- FUSED QKV gemm: one block computes Q,K,V 64x128 tiles ----------------
// grid (8=b, 8=n, 8=m). B (xnT tile) staged ONCE per K-iter, 3 A-panels -> 48 MFMA/barrier.
__global__ __launch_bounds__(256, 2) void gemm_qkv_kernel(
    const __bf16* __restrict__ wqkv, const float* __restrict__ qb,
    const float* __restrict__ kb, const float* __restrict__ vb,
    const __bf16* __restrict__ xnT,
    __bf16* __restrict__ qT, __bf16* __restrict__ kT, __bf16* __restrict__ vbuf)
{
  // 40 KB: Aq(0) Ak(4096) Av(8192) each 2 panels x 2048; Bs(12288) 2 panels x 4096.
  __shared__ __align__(16) __bf16 smem[20480];
  __bf16* Bs = smem + 12288;
  const int b = blockIdx.x;
  const int n0 = blockIdx.y * 128;
  const int m0 = blockIdx.z * 64;
  const __bf16* Aq = wqkv + (size_t)m0 * 512;
  const __bf16* Ak = Aq + 512 * 512;
  const __bf16* Av = Ak + 512 * 512;
  const __bf16* Bx = xnT + ((size_t)b * N_PIX + n0) * 512;

  const int tid = threadIdx.x, lane = tid & 63, wv = tid >> 6;
  const int quad = lane >> 4, l16 = lane & 15;
  const int wm = (wv >> 1) * 32, wn = (wv & 1) * 64;

  const f32x4_t zero = {0.f, 0.f, 0.f, 0.f};
  f32x4_t acc[3][2][4];
#pragma unroll
  for (int m = 0; m < 3; m++)
#pragma unroll
    for (int i = 0; i < 2; i++)
#pragma unroll
      for (int j = 0; j < 4; j++) acc[m][i][j] = zero;

  const int chA = wv * 64 + lane;
  const int rA = chA >> 2, kA = (chA & 3) * 8;
  const int chB0 = wv * 64 + lane, chB1 = 256 + wv * 64 + lane;
  const int rB0 = chB0 >> 2, kB0 = (chB0 & 3) * 8;
  const int rB1 = chB1 >> 2, kB1 = (chB1 & 3) * 8;

  for (int kt = 0; kt < 512; kt += 64) {
#pragma unroll
    for (int p = 0; p < 2; p++) {
      async16(Aq + (size_t)rA * 512 + kt + p * 32 + kA, smem + p * 2048 + (wv * 64) * 8);
      async16(Ak + (size_t)rA * 512 + kt + p * 32 + kA, smem + 4096 + p * 2048 + (wv * 64) * 8);
      async16(Av + (size_t)rA * 512 + kt + p * 32 + kA, smem + 8192 + p * 2048 + (wv * 64) * 8);
      async16(Bx + (size_t)rB0 * 512 + kt + p * 32 + kB0, Bs + p * 4096 + (wv * 64) * 8);
      async16(Bx + (size_t)rB1 * 512 + kt + p * 32 + kB1, Bs + p * 4096 + (256 + wv * 64) * 8);
    }
    __builtin_amdgcn_s_waitcnt(0);
    __syncthreads();
#pragma unroll
    for (int p = 0; p < 2; p++) {
      bf16x8_t bfr[4];
#pragma unroll
      for (int j = 0; j < 4; j++)
        bfr[j] = *(const bf16x8_t*)(Bs + p * 4096 + (wn + j * 16 + l16) * 32 + quad * 8);
#pragma unroll
      for (int m = 0; m < 3; m++) {
        bf16x8_t af[2];
#pragma unroll
        for (int i = 0; i < 2; i++)
          af[i] = *(const bf16x8_t*)(smem + m * 4096 + p * 2048 + (wm + i * 16 + l16) * 32 + quad * 8);
#pragma unroll
        for (int i = 0; i < 2; i++)
#pragma unroll
          for (int j = 0; j < 4; j++)
            acc[m][i][j] = __builtin_amdgcn_mfma_f32_16x16x32_bf16(af[i], bfr[j], acc[m][i][j], 0, 0, 0);
      }
    }
    __syncthreads();
  }

  // ---- epilogues (sequential, reuse smem; all coalesced via LDS transpose) ----
  const float qscale = 0.125f * 1.44269504f;   // HD^-0.5 * log2(e), folded into Q
#pragma unroll
  for (int mat = 0; mat < 2; mat++) {
    const float* bias = (mat == 0) ? qb : kb;
    const float sc = (mat == 0) ? qscale : 1.0f;
    __bf16* dst = (mat == 0) ? qT : kT;
#pragma unroll
    for (int i = 0; i < 2; i++) {
      const int crow = wm + i * 16 + quad * 4;
      const int o = m0 + crow;
      float b0 = bias[o], b1 = bias[o + 1], b2 = bias[o + 2], b3 = bias[o + 3];
#pragma unroll
      for (int j = 0; j < 4; j++) {
        const int nl = wn + j * 16 + l16;
        bf16x4_t pk;
        pk[0] = f2b((acc[mat][i][j][0] + b0) * sc);
        pk[1] = f2b((acc[mat][i][j][1] + b1) * sc);
        pk[2] = f2b((acc[mat][i][j][2] + b2) * sc);
        pk[3] = f2b((acc[mat][i][j][3] + b3) * sc);
        *(bf16x4_t*)(smem + nl * 72 + crow) = pk;
      }
    }
    __syncthreads();
#pragma unroll
    for (int it = 0; it < 4; it++) {
      const int n = it * 32 + (tid >> 3);
      const int c = (tid & 7) * 8;
      *(bf16x8_t*)(dst + ((size_t)b * N_PIX + n0 + n) * 512 + m0 + c) =
          *(const bf16x8_t*)(smem + n * 72 + c);
    }
    __syncthreads();
  }
  // V: [c][n] layout via stride-132 transpose
#pragma unroll
  for (int i = 0; i < 2; i++) {
    const int crow = wm + i * 16 + quad * 4;
    const int o = m0 + crow;
    float b0 = vb[o], b1 = vb[o + 1], b2 = vb[o + 2], b3 = vb[o + 3];
#pragma unroll
    for (int j = 0; j < 4; j++) {
      const int nl = wn + j * 16 + l16;
      smem[(crow + 0) * 132 + nl] = f2b(acc[2][i][j][0] + b0);
      smem[(crow + 1) * 132 + nl] = f2b(acc[2][i][j][1] + b1);
      smem[(crow + 2) * 132 + nl] = f2b(acc[2][i][j][2] + b2);
      smem[(crow + 3) * 132 + nl] = f2b(acc[2][i][j][3] + b3);
    }
  }
  __syncthreads();
  {
    const int c = tid >> 2;
    const int nch = (tid & 3) * 32;
    __bf16* vd = vbuf + ((size_t)b * 512 + m0 + c) * N_PIX + n0 + nch;
#pragma unroll
    for (int k = 0; k < 4; k++)
      *(bf16x8_t*)(vd + k * 8) = *(const bf16x8_t*)(smem + c * 132 + nch + k * 8);
  }
}

// ---------------- attention: 32 q/wave, permuted V, double-buffered, LDS-transposed out ----------------
__global__ __launch_bounds__(256, 2) void attn_kernel(
    const __bf16* __restrict__ qT, const __bf16* __restrict__ kT,
    const __bf16* __restrict__ vbuf, __bf16* __restrict__ aT)
{
  __shared__ __align__(16) __bf16 Ks[2][64 * 72];
  __shared__ __align__(16) __bf16 Vp[2][64 * 72];
  const int bh = blockIdx.x;
  const int b = bh >> 3, head = bh & 7;
  const int n0 = blockIdx.y * 128;
  const int tid = threadIdx.x, lane = tid & 63, wv = tid >> 6;
  const int quad = lane >> 4, l16 = lane & 15;

  bf16x8_t qf[2][2];
#pragma unroll
  for (int qt = 0; qt < 2; qt++) {
    const __bf16* qp = qT + ((size_t)b * N_PIX + n0 + wv * 32 + qt * 16 + l16) * 512 + head * 64;
    qf[qt][0] = *(const bf16x8_t*)(qp + quad * 8);
    qf[qt][1] = *(const bf16x8_t*)(qp + 32 + quad * 8);
  }

  const __bf16* kp = kT + ((size_t)b * N_PIX) * 512 + head * 64;
  const __bf16* vp = vbuf + ((size_t)b * 512 + head * 64) * N_PIX;

  const int srow = tid >> 2, scol = (tid & 3) * 16;
  const int pr0 = scol >> 5, hh0 = (scol >> 4) & 1;
  const int pos0 = pr0 * 32 + ((scol >> 2) & 3) * 8 + hh0 * 4;
  const int mc1 = scol + 8;
  const int pr1 = mc1 >> 5, hh1 = (mc1 >> 4) & 1;
  const int pos1 = pr1 * 32 + ((mc1 >> 2) & 3) * 8 + hh1 * 4;

  bf16x8_t kreg0 = *(const bf16x8_t*)(kp + (size_t)srow * 512 + scol);
  bf16x8_t kreg1 = *(const bf16x8_t*)(kp + (size_t)srow * 512 + scol + 8);
  bf16x8_t vreg0 = *(const bf16x8_t*)(vp + (size_t)srow * N_PIX + scol);
  bf16x8_t vreg1 = *(const bf16x8_t*)(vp + (size_t)srow * N_PIX + scol + 8);
  {
    *(bf16x8_t*)(Ks[0] + srow * 72 + scol)     = kreg0;
    *(bf16x8_t*)(Ks[0] + srow * 72 + scol + 8) = kreg1;
    bf16x4_t lo, hi;
#pragma unroll
    for (int r = 0; r < 4; r++) { lo[r] = vreg0[r]; hi[r] = vreg0[4 + r]; }
    *(bf16x4_t*)(Vp[0] + srow * 72 + pos0)     = lo;
    *(bf16x4_t*)(Vp[0] + srow * 72 + pos0 + 8) = hi;
#pragma unroll
    for (int r = 0; r < 4; r++) { lo[r] = vreg1[r]; hi[r] = vreg1[4 + r]; }
    *(bf16x4_t*)(Vp[0] + srow * 72 + pos1)     = lo;
    *(bf16x4_t*)(Vp[0] + srow * 72 + pos1 + 8) = hi;
  }
  kreg0 = *(const bf16x8_t*)(kp + (size_t)(64 + srow) * 512 + scol);
  kreg1 = *(const bf16x8_t*)(kp + (size_t)(64 + srow) * 512 + scol + 8);
  vreg0 = *(const bf16x8_t*)(vp + (size_t)srow * N_PIX + 64 + scol);
  vreg1 = *(const bf16x8_t*)(vp + (size_t)srow * N_PIX + 64 + scol + 8);
  __syncthreads();

  const f32x4_t zero = {0.f, 0.f, 0.f, 0.f};
  f32x4_t oacc[2][4];
#pragma unroll
  for (int qt = 0; qt < 2; qt++)
#pragma unroll
    for (int jc = 0; jc < 4; jc++) oacc[qt][jc] = zero;
  f32x4_t lsum4[2] = {zero, zero};

  for (int mt = 0; mt < 16; mt++) {
    const int cur = mt & 1, nxt = cur ^ 1;
    const __bf16* Kc = Ks[cur];
    const __bf16* Vc = Vp[cur];

    f32x4_t sacc[2][4];
#pragma unroll
    for (int mb = 0; mb < 4; mb++) {
      bf16x8_t kf0 = *(const bf16x8_t*)(Kc + (mb * 16 + l16) * 72 + quad * 8);
      bf16x8_t kf1 = *(const bf16x8_t*)(Kc + (mb * 16 + l16) * 72 + 32 + quad * 8);
#pragma unroll
      for (int qt = 0; qt < 2; qt++) {
        f32x4_t s = zero;
        s = __builtin_amdgcn_mfma_f32_16x16x32_bf16(kf0, qf[qt][0], s, 0, 0, 0);
        s = __builtin_amdgcn_mfma_f32_16x16x32_bf16(kf1, qf[qt][1], s, 0, 0, 0);
        sacc[qt][mb] = s;
      }
    }

    bf16x8_t pf[2][2];
#pragma unroll
    for (int qt = 0; qt < 2; qt++) {
      float p[4][4];
#pragma unroll
      for (int mb = 0; mb < 4; mb++)
#pragma unroll
        for (int r = 0; r < 4; r++) {
          p[mb][r] = __builtin_amdgcn_exp2f(sacc[qt][mb][r]);
          lsum4[qt][r] += p[mb][r];
        }
#pragma unroll
      for (int pr = 0; pr < 2; pr++) {
        u32x4_t u;
        u[0] = pack_trunc(p[2 * pr][0],     p[2 * pr][1]);
        u[1] = pack_trunc(p[2 * pr][2],     p[2 * pr][3]);
        u[2] = pack_trunc(p[2 * pr + 1][0], p[2 * pr + 1][1]);
        u[3] = pack_trunc(p[2 * pr + 1][2], p[2 * pr + 1][3]);
        pf[qt][pr] = __builtin_bit_cast(bf16x8_t, u);
      }
    }

#pragma unroll
    for (int jc = 0; jc < 4; jc++) {
      const int vrow = (jc * 16 + l16) * 72;
#pragma unroll
      for (int pr = 0; pr < 2; pr++) {
        bf16x8_t vf = *(const bf16x8_t*)(Vc + vrow + pr * 32 + quad * 8);
#pragma unroll
        for (int qt = 0; qt < 2; qt++)
          oacc[qt][jc] = __builtin_amdgcn_mfma_f32_16x16x32_bf16(vf, pf[qt][pr], oacc[qt][jc], 0, 0, 0);
      }
    }

    if (mt < 15) {
      *(bf16x8_t*)(Ks[nxt] + srow * 72 + scol)     = kreg0;
      *(bf16x8_t*)(Ks[nxt] + srow * 72 + scol + 8) = kreg1;
      bf16x4_t lo, hi;
#pragma unroll
      for (int r = 0; r < 4; r++) { lo[r] = vreg0[r]; hi[r] = vreg0[4 + r]; }
      *(bf16x4_t*)(Vp[nxt] + srow * 72 + pos0)     = lo;
      *(bf16x4_t*)(Vp[nxt] + srow * 72 + pos0 + 8) = hi;
#pragma unroll
      for (int r = 0; r < 4; r++) { lo[r] = vreg1[r]; hi[r] = vreg1[4 + r]; }
      *(bf16x4_t*)(Vp[nxt] + srow * 72 + pos1)     = lo;
      *(bf16x4_t*)(Vp[nxt] + srow * 72 + pos1 + 8) = hi;
      if (mt < 14) {
        kreg0 = *(const bf16x8_t*)(kp + (size_t)((mt + 2) * 64 + srow) * 512 + scol);
        kreg1 = *(const bf16x8_t*)(kp + (size_t)((mt + 2) * 64 + srow) * 512 + scol + 8);
        vreg0 = *(const bf16x8_t*)(vp + (size_t)srow * N_PIX + (mt + 2) * 64 + scol);
        vreg1 = *(const bf16x8_t*)(vp + (size_t)srow * N_PIX + (mt + 2) * 64 + scol + 8);
      }
      __syncthreads();
    }
  }

  // O epilogue: normalize, transpose through LDS (reuse Ks), coalesced stores
  __syncthreads();
  __bf16* Tr = &Ks[0][0];
#pragma unroll
  for (int qt = 0; qt < 2; qt++) {
    float lsum = lsum4[qt][0] + lsum4[qt][1] + lsum4[qt][2] + lsum4[qt][3];
    lsum += __shfl_xor(lsum, 16, 64);
    lsum += __shfl_xor(lsum, 32, 64);
    const float inv = 1.f / lsum;
    const int nl = wv * 32 + qt * 16 + l16;
#pragma unroll
    for (int jc = 0; jc < 4; jc++) {
      bf16x4_t o4;
#pragma unroll
      for (int r = 0; r < 4; r++) o4[r] = f2b(oacc[qt][jc][r] * inv);
      *(bf16x4_t*)(Tr + nl * 72 + jc * 16 + quad * 4) = o4;
    }
  }
  __syncthreads();
#pragma unroll
  for (int it = 0; it < 4; it++) {
    const int n = it * 32 + (tid >> 3);
    const int c = (tid & 7) * 8;
    *(bf16x8_t*)(aT + ((size_t)b * N_PIX + n0 + n) * 512 + head * 64 + c) =
        *(const bf16x8_t*)(Tr + n * 72 + c);
  }
}

// ---------------- proj gemm + bias + residual: 64x128 tiles, grid (8=b, 8=n, 8=m) ----------------
__global__ __launch_bounds__(256, 4) void gemm_proj_kernel(
    const __bf16* __restrict__ wp, const float* __restrict__ pb,
    const __bf16* __restrict__ aT, const float* __restrict__ x,
    float* __restrict__ out)
{
  __shared__ __align__(16) __bf16 smem[12288];
  __bf16* As = smem;
  __bf16* Bs = smem + 4096;
  const int b = blockIdx.x;
  const int n0 = blockIdx.y * 128;
  const int m0 = blockIdx.z * 64;
  const __bf16* A = wp + (size_t)m0 * 512;
  const __bf16* B = aT + ((size_t)b * N_PIX + n0) * 512;
  f32x4_t acc[2][4];
  gemm_core_64(A, B, As, Bs, acc);
  const int tid = threadIdx.x, lane = tid & 63, wv = tid >> 6;
  const int quad = lane >> 4, l16 = lane & 15;
  const int wm = (wv >> 1) * 32, wn = (wv & 1) * 64;
#pragma unroll
  for (int i = 0; i < 2; i++) {
    const int o = m0 + wm + i * 16 + quad * 4;
#pragma unroll
    for (int j = 0; j < 4; j++) {
      const int n = n0 + wn + j * 16 + l16;
#pragma unroll
      for (int r = 0; r < 4; r++) {
        size_t idx = ((size_t)b * 512 + o + r) * N_PIX + n;
        out[idx] = acc[i][j][r] + pb[o + r] + x[idx];
      }
    }
  }
}

extern "C" void kernel_launch(void* const* d_in, const int* in_sizes, int n_in,
                              void* d_out, int out_size, void* d_ws, size_t ws_size,
                              hipStream_t stream)
{
  (void)in_sizes; (void)n_in; (void)out_size; (void)ws_size;
  const float* x   = (const float*)d_in[0];
  const float* gnw = (const float*)d_in[1];
  const float* gnb = (const float*)d_in[2];
  const float* qw  = (const float*)d_in[3];
  const float* qb  = (const float*)d_in[4];
  const float* kw  = (const float*)d_in[5];
  const float* kb  = (const float*)d_in[6];
  const float* vw  = (const float*)d_in[7];
  const float* vb  = (const float*)d_in[8];
  const float* pw  = (const float*)d_in[9];
  const float* pb  = (const float*)d_in[10];
  float* out = (float*)d_out;

  char* ws = (char*)d_ws;
  __bf16* wb   = (__bf16*)(ws);                         // 2 MB
  __bf16* xnT  = (__bf16*)(ws + (size_t)(2  << 20));    // 8 MB
  __bf16* qTb  = (__bf16*)(ws + (size_t)(10 << 20));    // 8 MB
  __bf16* kTb  = (__bf16*)(ws + (size_t)(18 << 20));    // 8 MB
  __bf16* vbf  = (__bf16*)(ws + (size_t)(26 << 20));    // 8 MB
  __bf16* aT   = (__bf16*)(ws + (size_t)(34 << 20));    // 8 MB
  float2* psum = (float2*)(ws + (size_t)(42 << 20));    // 4 KB

  hipLaunchKernelGGL(prep_kernel, dim3(1536), dim3(256), 0, stream,
                     qw, kw, vw, pw, wb, x, psum);
  hipLaunchKernelGGL(gn_apply_kernel, dim3(32, 8), dim3(256), 0, stream, x, psum, gnw, gnb, xnT);
  hipLaunchKernelGGL(gemm_qkv_kernel, dim3(8, 8, 8), dim3(256), 0, stream,
                     wb, qb, kb, vb, xnT, qTb, kTb, vbf);
  hipLaunchKernelGGL(attn_kernel, dim3(64, 8), dim3(256), 0, stream, qTb, kTb, vbf, aT);
  hipLaunchKernelGGL(gemm_proj_kernel, dim3(8, 8, 8), dim3(256), 0, stream,
                     wb + (size_t)3 * 512 * 512, pb, aT, x, out);
}